// Round 4
// baseline (880.078 us; speedup 1.0000x reference)
//
#include <hip/hip_runtime.h>
#include <hip/hip_bf16.h>
#include <math.h>

#define BB    32
#define SS    1024
#define HID   1024
#define AT    512
#define NVOC  1000
#define NT    (BB*SS)

typedef unsigned short u16;
typedef __attribute__((ext_vector_type(8))) short s16x8;   // 8 bf16 (4 VGPRs)
typedef __attribute__((ext_vector_type(4))) float f32x4;   // MFMA acc

__device__ __forceinline__ float bf2f(u16 u) {
    union { unsigned int i; float f; } x; x.i = ((unsigned int)u) << 16; return x.f;
}
__device__ __forceinline__ u16 f2bf(float f) {
    union { float f; unsigned int i; } u; u.f = f;
    unsigned int r = u.i + 0x7fffu + ((u.i >> 16) & 1u);
    return (u16)(r >> 16);
}
__device__ __forceinline__ float4 ld4(const float* p) { return *(const float4*)p; }
__device__ __forceinline__ float4 ld4bf(const u16* p) {
    ushort4 v = *(const ushort4*)p;
    return make_float4(bf2f(v.x), bf2f(v.y), bf2f(v.z), bf2f(v.w));
}

struct Ptrs4f { const float* p[4]; };

__device__ __forceinline__ float blockReduceSum(float x) {
    #pragma unroll
    for (int off = 32; off > 0; off >>= 1) x += __shfl_down(x, off, 64);
    __shared__ float tmp[4];
    int lane = threadIdx.x & 63, wid = threadIdx.x >> 6;
    if (lane == 0) tmp[wid] = x;
    __syncthreads();
    if (threadIdx.x == 0) x = tmp[0] + tmp[1] + tmp[2] + tmp[3];
    return x; // valid on thread 0 only
}

// ---------------- PE table (fp32) + bf16 copy ----------------
__global__ void k_pe(float* __restrict__ PE) {
    int s = blockIdx.x, i = threadIdx.x;               // 512 threads
    float denom = powf(10000.f, (2.f * (float)i) / 1024.f);
    float ang = (float)s / denom;
    PE[(long)s*1024 + 2*i]     = sinf(ang);
    PE[(long)s*1024 + 2*i + 1] = cosf(ang);
}
__global__ void k_cvt(const float* __restrict__ in, u16* __restrict__ out, int n) {
    int i = blockIdx.x*256 + threadIdx.x;
    if (i < n) out[i] = f2bf(in[i]);
}
__global__ void k_cvtE(Ptrs4f E, u16* __restrict__ out) {
    int f = blockIdx.y;
    int i = blockIdx.x*256 + threadIdx.x;               // 0..127999
    if (i < 128000) out[(size_t)f*128000 + i] = f2bf(E.p[f][i]);
}

// ---------------- transpose fp32 -> bf16: out[c][r] = in[r][c] ----------------
__global__ void k_transp(Ptrs4f src, u16* __restrict__ dst, int R, int C) {
    const float* in = src.p[blockIdx.z];
    u16* out = dst + (size_t)blockIdx.z * R * C;
    int r0 = blockIdx.y*32, c0 = blockIdx.x*32;
    __shared__ float tt[32][33];
    tt[threadIdx.y][threadIdx.x] = in[(size_t)(r0 + threadIdx.y)*C + c0 + threadIdx.x];
    __syncthreads();
    out[(size_t)(c0 + threadIdx.y)*R + r0 + threadIdx.x] = f2bf(tt[threadIdx.x][threadIdx.y]);
}

// ---------------- W0f = W0@Wf, Wcp = Wc@Wproj_bot (all fp32) ----------------
__global__ void k_w0f_wcp(const float* __restrict__ Wc, const float* __restrict__ Wproj,
                          const float* __restrict__ W0, const float* __restrict__ Wf,
                          float* __restrict__ Wcp, float* __restrict__ W0f) {
    int blk = blockIdx.x, tid = threadIdx.x;
    if (blk < 4) {
        float acc[4] = {0,0,0,0};
        for (int j = 0; j < 512; ++j) {
            float wc = Wc[blk*512 + j];
            const float* row = Wproj + (size_t)(512 + j)*1024;
            #pragma unroll
            for (int ii = 0; ii < 4; ++ii) acc[ii] += wc * row[tid + ii*256];
        }
        #pragma unroll
        for (int ii = 0; ii < 4; ++ii) Wcp[blk*1024 + tid + ii*256] = acc[ii];
    } else {
        for (int ii = 0; ii < 4; ++ii) {
            int i = tid + ii*256;
            float a = 0.f;
            for (int j = 0; j < 1024; ++j) a += W0[(size_t)i*1024 + j] * Wf[j];
            W0f[i] = a;
        }
    }
}

// ---------------- v_h = WV_h @ W0f_h ; CQ_w = Wcp @ W_w (fp32) ----------------
__global__ void k_v_cq(Ptrs4f W, const float* __restrict__ WV1, const float* __restrict__ WV2,
                       const float* __restrict__ W0f, const float* __restrict__ Wcp,
                       float* __restrict__ v, float* __restrict__ CQ) {
    int blk = blockIdx.x, tid = threadIdx.x;
    if (blk < 16) {
        int w = blk & 3, c = blk >> 2;
        const float* Ww = W.p[w];
        float a0 = 0.f, a1 = 0.f;
        for (int j = 0; j < 1024; ++j) {
            float wv = Wcp[c*1024 + j];
            a0 += wv * Ww[(size_t)j*512 + tid];
            a1 += wv * Ww[(size_t)j*512 + tid + 256];
        }
        CQ[(size_t)(w*4 + c)*512 + tid]       = a0;
        CQ[(size_t)(w*4 + c)*512 + tid + 256] = a1;
    } else {
        int h = blk - 16;
        const float* WV = h ? WV2 : WV1;
        const float* wf = W0f + h*512;
        for (int ii = 0; ii < 4; ++ii) {
            int i = tid + ii*256;
            float a = 0.f;
            for (int aa = 0; aa < 512; ++aa) a += WV[(size_t)i*512 + aa] * wf[aa];
            v[h*1024 + i] = a;
        }
    }
}

// ---------------- MFMA GEMM: C[M,N] = alpha * A[M,K] @ B[N,K]^T (bf16 in) ----------------
__device__ __forceinline__ void cstore(float* p, float v) { *p = v; }
__device__ __forceinline__ void cstore(u16* p, float v)   { *p = f2bf(v); }

template<typename CT>
__device__ __forceinline__ void mfma_gemm(const u16* __restrict__ A, const u16* __restrict__ B,
                                          CT* __restrict__ C, int M, int N, int K, float alpha) {
    __shared__ u16 As[128*40];   // row stride 40 (80B): +16B pad, 16B-aligned
    __shared__ u16 Bs[128*40];
    const int tid = threadIdx.x;
    const int wave = tid >> 6, lane = tid & 63;
    const int quad = lane >> 4, l16 = lane & 15;
    const int m0 = blockIdx.y*128, n0 = blockIdx.x*128;
    const int wm = (wave >> 1)*64, wn = (wave & 1)*64;
    const int srow = tid >> 2, schunk = tid & 3;
    f32x4 acc[4][4] = {};

    for (int k0 = 0; k0 < K; k0 += 32) {
        #pragma unroll
        for (int rr = 0; rr < 2; ++rr) {
            int row = srow + rr*64;
            int gm = m0 + row, gn = n0 + row;
            uint4 av = make_uint4(0,0,0,0), bv = make_uint4(0,0,0,0);
            if (gm < M) av = *(const uint4*)(A + (size_t)gm*K + k0 + schunk*8);
            if (gn < N) bv = *(const uint4*)(B + (size_t)gn*K + k0 + schunk*8);
            *(uint4*)(As + row*40 + schunk*8) = av;
            *(uint4*)(Bs + row*40 + schunk*8) = bv;
        }
        __syncthreads();
        s16x8 af[4], bf[4];
        #pragma unroll
        for (int i = 0; i < 4; ++i) af[i] = *(const s16x8*)(As + (wm + i*16 + l16)*40 + quad*8);
        #pragma unroll
        for (int j = 0; j < 4; ++j) bf[j] = *(const s16x8*)(Bs + (wn + j*16 + l16)*40 + quad*8);
        #pragma unroll
        for (int i = 0; i < 4; ++i)
            #pragma unroll
            for (int j = 0; j < 4; ++j)
                acc[i][j] = __builtin_amdgcn_mfma_f32_16x16x32_bf16(af[i], bf[j], acc[i][j], 0, 0, 0);
        __syncthreads();
    }
    // C/D layout: col = lane&15, row = quad*4 + reg  [measured m89/m91]
    #pragma unroll
    for (int i = 0; i < 4; ++i) {
        #pragma unroll
        for (int r = 0; r < 4; ++r) {
            int gm = m0 + wm + i*16 + quad*4 + r;
            if (gm < M) {
                #pragma unroll
                for (int j = 0; j < 4; ++j) {
                    int gn = n0 + wn + j*16 + l16;
                    cstore(C + (size_t)gm*N + gn, acc[i][j][r] * alpha);
                }
            }
        }
    }
}

__global__ __launch_bounds__(256) void k_g_T16(const u16* __restrict__ E16, const u16* __restrict__ WpT, u16* __restrict__ T16) {
    int f = blockIdx.z;
    mfma_gemm<u16>(E16 + (size_t)f*1000*128, WpT + (size_t)f*1024*128, T16 + (size_t)f*1000*1024, 1000, 1024, 128, 1.f);
}
__global__ __launch_bounds__(256) void k_g_TQK(const u16* __restrict__ T16, const u16* __restrict__ Wt, u16* __restrict__ TQK16) {
    int f = blockIdx.z >> 2;
    mfma_gemm<u16>(T16 + (size_t)f*1000*1024, Wt + (size_t)(blockIdx.z & 3)*512*1024,
                   TQK16 + (size_t)blockIdx.z*1000*512, 1000, 512, 1024, 1.f);
}
__global__ __launch_bounds__(256) void k_g_PEQ(const u16* __restrict__ PE16, const u16* __restrict__ Wt, u16* __restrict__ PEQ16) {
    mfma_gemm<u16>(PE16, Wt + (size_t)blockIdx.z*512*1024, PEQ16 + (size_t)blockIdx.z*1024*512, 1024, 512, 1024, 1.f);
}
__global__ __launch_bounds__(256) void k_g_S(const u16* __restrict__ Q, const u16* __restrict__ K,
                                             float* __restrict__ Sb, float alpha) {
    size_t b = blockIdx.z;
    mfma_gemm<float>(Q + b*SS*AT, K + b*SS*AT, Sb + b*SS*SS, 1024, 1024, 512, alpha);
}

// ---------------- small dot products: Ut, pu, cu ----------------
__global__ void k_dots(const u16* __restrict__ T16, const float* __restrict__ PE,
                       const float* __restrict__ Wcp, const float* __restrict__ v,
                       float* __restrict__ Ut, float* __restrict__ pu, float* __restrict__ cu) {
    int id = blockIdx.x;
    float p;
    if (id < 8000) {
        int f = id / 2000, rem = id % 2000, h = rem / 1000, r = rem % 1000;
        float4 a = ld4bf(T16 + ((size_t)f*1000 + r)*1024 + threadIdx.x*4);
        float4 b = ld4(v + h*1024 + threadIdx.x*4);
        p = a.x*b.x + a.y*b.y + a.z*b.z + a.w*b.w;
        p = blockReduceSum(p);
        if (threadIdx.x == 0) Ut[(size_t)(f*2 + h)*1000 + r] = p;
    } else if (id < 10048) {
        int tq = id - 8000; int h = tq >> 10, s = tq & 1023;
        float4 a = ld4(PE + (size_t)s*1024 + threadIdx.x*4);
        float4 b = ld4(v + h*1024 + threadIdx.x*4);
        p = a.x*b.x + a.y*b.y + a.z*b.z + a.w*b.w;
        p = blockReduceSum(p);
        if (threadIdx.x == 0) pu[h*1024 + s] = p;
    } else {
        int tq = id - 10048; int h = tq >> 2, c = tq & 3;
        float4 a = ld4(Wcp + c*1024 + threadIdx.x*4);
        float4 b = ld4(v + h*1024 + threadIdx.x*4);
        p = a.x*b.x + a.y*b.y + a.z*b.z + a.w*b.w;
        p = blockReduceSum(p);
        if (threadIdx.x == 0) cu[h*4 + c] = p;
    }
}

// ---------------- gather for head h: Q,K rows (bf16) + u ----------------
__global__ void k_gather(const int* __restrict__ cate, const float* __restrict__ cont,
                         const u16* __restrict__ TQK, const float* __restrict__ CQ,
                         const u16* __restrict__ PEQ, const float* __restrict__ Ut,
                         const float* __restrict__ cu, const float* __restrict__ pu,
                         u16* __restrict__ Qh, u16* __restrict__ Kh,
                         float* __restrict__ u, int h) {
    size_t t = blockIdx.x; int s = (int)(t & 1023);
    int tid = threadIdx.x;
    int c0 = cate[t*4+0], c1 = cate[t*4+1], c2 = cate[t*4+2], c3 = cate[t*4+3];
    float cv0 = cont[t*4+0], cv1 = cont[t*4+1];
    float cv2 = cont[t*4+2], cv3 = cont[t*4+3];
    int n = tid*2;
    #pragma unroll
    for (int e = 0; e < 2; ++e) {
        int w = 2*h + e;
        const u16* t0 = TQK + ((size_t)(0  + w)*1000 + c0)*512;
        const u16* t1 = TQK + ((size_t)(4  + w)*1000 + c1)*512;
        const u16* t2 = TQK + ((size_t)(8  + w)*1000 + c2)*512;
        const u16* t3 = TQK + ((size_t)(12 + w)*1000 + c3)*512;
        const u16* pq = PEQ + ((size_t)w*1024 + s)*512;
        const float* cq = CQ + (size_t)w*2048;
        float x0 = bf2f(t0[n]) + bf2f(t1[n]) + bf2f(t2[n]) + bf2f(t3[n]) + bf2f(pq[n])
                 + cv0*cq[n] + cv1*cq[512+n] + cv2*cq[1024+n] + cv3*cq[1536+n];
        float x1 = bf2f(t0[n+1]) + bf2f(t1[n+1]) + bf2f(t2[n+1]) + bf2f(t3[n+1]) + bf2f(pq[n+1])
                 + cv0*cq[n+1] + cv1*cq[512+n+1] + cv2*cq[1024+n+1] + cv3*cq[1536+n+1];
        u16* op = (e ? Kh : Qh) + t*512;
        unsigned int pack = ((unsigned int)f2bf(x1) << 16) | f2bf(x0);
        *(unsigned int*)(op + n) = pack;
    }
    if (tid == 0) {
        float uu = pu[h*1024 + s]
                 + Ut[(0*2 + h)*1000 + c0] + Ut[(1*2 + h)*1000 + c1]
                 + Ut[(2*2 + h)*1000 + c2] + Ut[(3*2 + h)*1000 + c3]
                 + cv0*cu[h*4+0] + cv1*cu[h*4+1] + cv2*cu[h*4+2] + cv3*cu[h*4+3];
        u[(size_t)h*NT + t] = uu;
    }
}

// ---------------- column (query-axis) softmax stats ----------------
__global__ void k_stats_partial(const float* __restrict__ Sb, float* __restrict__ Pm,
                                float* __restrict__ Pd, int b0) {
    int kc = blockIdx.x, qc = blockIdx.y, bl = blockIdx.z;
    int k = kc*256 + threadIdx.x;
    const float* base = Sb + ((size_t)bl*1024 + qc*256)*1024 + k;
    float mx = -3.4e38f;
    for (int q = 0; q < 256; ++q) mx = fmaxf(mx, base[(size_t)q*1024]);
    float sm = 0.f;
    for (int q = 0; q < 256; ++q) sm += expf(base[(size_t)q*1024] - mx);
    Pm[((size_t)(b0 + bl)*4 + qc)*1024 + k] = mx;
    Pd[((size_t)(b0 + bl)*4 + qc)*1024 + k] = sm;
}

__global__ void k_stats_combine(const float* __restrict__ Pm, const float* __restrict__ Pd,
                                const float* __restrict__ u, float* __restrict__ m,
                                float* __restrict__ w, int b0) {
    int idx = b0*1024 + blockIdx.x*256 + threadIdx.x;   // b*1024 + k
    int b = idx >> 10, k = idx & 1023;
    float mx = -3.4e38f;
    #pragma unroll
    for (int qc = 0; qc < 4; ++qc) mx = fmaxf(mx, Pm[((size_t)b*4 + qc)*1024 + k]);
    float dd = 0.f;
    #pragma unroll
    for (int qc = 0; qc < 4; ++qc) dd += Pd[((size_t)b*4 + qc)*1024 + k]
                                       * expf(Pm[((size_t)b*4 + qc)*1024 + k] - mx);
    m[idx] = mx;
    w[idx] = u[idx] / dd;
}

// ---------------- logits ----------------
__global__ void k_logit(const float* __restrict__ Sb, const float* __restrict__ m,
                        const float* __restrict__ w, float* __restrict__ logits,
                        int b0, int init) {
    size_t tl = blockIdx.x;                  // local row within chunk
    size_t tabs = (size_t)b0*1024 + tl;
    int b = (int)(tabs >> 10);
    const float* row = Sb + tl*1024;
    const float* mb = m + (size_t)b*1024;
    const float* wb = w + (size_t)b*1024;
    float acc = 0.f;
    for (int k = threadIdx.x; k < 1024; k += 256) acc += expf(row[k] - mb[k]) * wb[k];
    acc = blockReduceSum(acc);
    if (threadIdx.x == 0) { if (init) logits[tabs] = acc; else logits[tabs] += acc; }
}

// Output is FLOAT32 (reference returns fp32; harness reads fp32) — R0-R3 wrote bf16
// and left half the buffer zeroed, which was the 0.457 absmax.
__global__ void k_final(const float* __restrict__ logits, float* __restrict__ out) {
    int t = blockIdx.x*256 + threadIdx.x;
    float x = logits[t];
    out[t] = 1.f / (1.f + expf(-x));
}

extern "C" void kernel_launch(void* const* d_in, const int* in_sizes, int n_in,
                              void* d_out, int out_size, void* d_ws, size_t ws_size,
                              hipStream_t stream) {
    const int*   cate = (const int*)d_in[0];
    const float* cont = (const float*)d_in[1];
    Ptrs4f E; E.p[0] = (const float*)d_in[4]; E.p[1] = (const float*)d_in[5];
              E.p[2] = (const float*)d_in[6]; E.p[3] = (const float*)d_in[7];
    const float* Wc    = (const float*)d_in[8];
    const float* Wproj = (const float*)d_in[9];
    Ptrs4f W; W.p[0] = (const float*)d_in[10];  // WQ1
              W.p[1] = (const float*)d_in[11];  // WK1
              W.p[2] = (const float*)d_in[13];  // WQ2
              W.p[3] = (const float*)d_in[14];  // WK2
    const float* WV1 = (const float*)d_in[12];
    const float* WV2 = (const float*)d_in[15];
    const float* W0  = (const float*)d_in[16];
    const float* Wf  = (const float*)d_in[17];

    char* base = (char*)d_ws;
    size_t off = 0;
    auto alloc = [&](size_t bytes) { void* p = base + off; off += (bytes + 255) & ~(size_t)255; return p; };
    float* PE    = (float*)alloc(1048576ull*4);
    u16*   PE16  = (u16*)  alloc(1048576ull*2);
    u16*   E16   = (u16*)  alloc(4ull*1000*128*2);
    u16*   Wt    = (u16*)  alloc(4ull*512*1024*2);
    u16*   WpT   = (u16*)  alloc(4ull*1024*128*2);
    u16*   T16   = (u16*)  alloc(4ull*1000*1024*2);
    u16*   TQK16 = (u16*)  alloc(16ull*1000*512*2);
    u16*   PEQ16 = (u16*)  alloc(4ull*1024*512*2);
    float* Wcp   = (float*)alloc(4*1024*4);
    float* W0f   = (float*)alloc(1024*4);
    float* vv    = (float*)alloc(2*1024*4);
    float* CQ    = (float*)alloc(16*512*4);
    float* Ut    = (float*)alloc(8*1000*4);
    float* cu    = (float*)alloc(8*4);
    float* pu    = (float*)alloc(2*1024*4);
    float* ubuf  = (float*)alloc(2ull*NT*4);
    u16*   Qh    = (u16*)  alloc((size_t)NT*512*2);
    u16*   Kh    = (u16*)  alloc((size_t)NT*512*2);
    float* Pm    = (float*)alloc(32ull*4*1024*4);
    float* Pd    = (float*)alloc(32ull*4*1024*4);
    float* mbuf  = (float*)alloc(32*1024*4);
    float* wbuf  = (float*)alloc(32*1024*4);
    float* logits= (float*)alloc((size_t)NT*4);
    size_t sChunkBytes = (size_t)SS*SS*4;
    size_t remain = (ws_size > off) ? (ws_size - off) : 0;
    int NB = (int)(remain / sChunkBytes);
    if (NB > 32) NB = 32;
    if (NB < 1) NB = 1;
    float* Sbuf = (float*)(base + off);

    const float alpha = 0.044194173824159216f;   // 1/sqrt(512)

    k_pe<<<1024, 512, 0, stream>>>(PE);
    k_cvt<<<4096, 256, 0, stream>>>(PE, PE16, 1048576);
    k_cvtE<<<dim3(500, 4), 256, 0, stream>>>(E, E16);
    k_transp<<<dim3(16, 32, 4), dim3(32, 32), 0, stream>>>(W, Wt, 1024, 512);
    Ptrs4f Wp4; for (int f = 0; f < 4; ++f) Wp4.p[f] = Wproj + (size_t)f*128*1024;
    k_transp<<<dim3(32, 4, 4), dim3(32, 32), 0, stream>>>(Wp4, WpT, 128, 1024);
    k_w0f_wcp<<<5, 256, 0, stream>>>(Wc, Wproj, W0, Wf, Wcp, W0f);
    k_v_cq<<<18, 256, 0, stream>>>(W, WV1, WV2, W0f, Wcp, vv, CQ);
    k_g_T16<<<dim3(8, 8, 4), 256, 0, stream>>>(E16, WpT, T16);
    k_g_TQK<<<dim3(4, 8, 16), 256, 0, stream>>>(T16, Wt, TQK16);
    k_g_PEQ<<<dim3(4, 8, 4), 256, 0, stream>>>(PE16, Wt, PEQ16);
    k_dots<<<10056, 256, 0, stream>>>(T16, PE, Wcp, vv, Ut, pu, cu);

    for (int h = 0; h < 2; ++h) {
        k_gather<<<NT, 256, 0, stream>>>(cate, cont, TQK16, CQ, PEQ16, Ut, cu, pu, Qh, Kh, ubuf, h);
        for (int b0 = 0; b0 < 32; b0 += NB) {
            int nb = (32 - b0 < NB) ? (32 - b0) : NB;
            k_g_S<<<dim3(8, 8, nb), 256, 0, stream>>>(Qh + (size_t)b0*SS*AT, Kh + (size_t)b0*SS*AT, Sbuf, alpha);
            k_stats_partial<<<dim3(4, 4, nb), 256, 0, stream>>>(Sbuf, Pm, Pd, b0);
            k_stats_combine<<<nb*4, 256, 0, stream>>>(Pm, Pd, ubuf + (size_t)h*NT, mbuf, wbuf, b0);
            k_logit<<<nb*SS, 256, 0, stream>>>(Sbuf, mbuf, wbuf, logits, b0, h == 0 ? 1 : 0);
        }
    }
    k_final<<<128, 256, 0, stream>>>(logits, (float*)d_out);
}

// Round 5
// 582.750 us; speedup vs baseline: 1.5102x; 1.5102x over previous
//
#include <hip/hip_runtime.h>
#include <hip/hip_bf16.h>
#include <math.h>

#define BB    32
#define SS    1024
#define HID   1024
#define AT    512
#define NVOC  1000
#define NT    (BB*SS)

typedef unsigned short u16;
typedef __attribute__((ext_vector_type(8))) short s16x8;   // 8 bf16 (4 VGPRs)
typedef __attribute__((ext_vector_type(4))) float f32x4;   // MFMA acc

__device__ __forceinline__ float bf2f(u16 u) {
    union { unsigned int i; float f; } x; x.i = ((unsigned int)u) << 16; return x.f;
}
__device__ __forceinline__ u16 f2bf(float f) {
    union { float f; unsigned int i; } u; u.f = f;
    unsigned int r = u.i + 0x7fffu + ((u.i >> 16) & 1u);
    return (u16)(r >> 16);
}
__device__ __forceinline__ float4 ld4(const float* p) { return *(const float4*)p; }
__device__ __forceinline__ float4 ld4bf(const u16* p) {
    ushort4 v = *(const ushort4*)p;
    return make_float4(bf2f(v.x), bf2f(v.y), bf2f(v.z), bf2f(v.w));
}

struct Ptrs4f { const float* p[4]; };

__device__ __forceinline__ float blockReduceSum(float x) {
    #pragma unroll
    for (int off = 32; off > 0; off >>= 1) x += __shfl_down(x, off, 64);
    __shared__ float tmp[4];
    int lane = threadIdx.x & 63, wid = threadIdx.x >> 6;
    if (lane == 0) tmp[wid] = x;
    __syncthreads();
    if (threadIdx.x == 0) x = tmp[0] + tmp[1] + tmp[2] + tmp[3];
    return x; // valid on thread 0 only
}

// ---------------- PE table (fp32) + bf16 copy ----------------
__global__ void k_pe(float* __restrict__ PE) {
    int s = blockIdx.x, i = threadIdx.x;               // 512 threads
    float denom = powf(10000.f, (2.f * (float)i) / 1024.f);
    float ang = (float)s / denom;
    PE[(long)s*1024 + 2*i]     = sinf(ang);
    PE[(long)s*1024 + 2*i + 1] = cosf(ang);
}
__global__ void k_cvt(const float* __restrict__ in, u16* __restrict__ out, int n) {
    int i = blockIdx.x*256 + threadIdx.x;
    if (i < n) out[i] = f2bf(in[i]);
}
__global__ void k_cvtE(Ptrs4f E, u16* __restrict__ out) {
    int f = blockIdx.y;
    int i = blockIdx.x*256 + threadIdx.x;               // 0..127999
    if (i < 128000) out[(size_t)f*128000 + i] = f2bf(E.p[f][i]);
}

// ---------------- transpose fp32 -> bf16: out[c][r] = in[r][c] ----------------
__global__ void k_transp(Ptrs4f src, u16* __restrict__ dst, int R, int C) {
    const float* in = src.p[blockIdx.z];
    u16* out = dst + (size_t)blockIdx.z * R * C;
    int r0 = blockIdx.y*32, c0 = blockIdx.x*32;
    __shared__ float tt[32][33];
    tt[threadIdx.y][threadIdx.x] = in[(size_t)(r0 + threadIdx.y)*C + c0 + threadIdx.x];
    __syncthreads();
    out[(size_t)(c0 + threadIdx.y)*R + r0 + threadIdx.x] = f2bf(tt[threadIdx.x][threadIdx.y]);
}

// ---------------- stage A: W0f rows (1024 blk) + Wcp (16 blk) + CQ zero (32 blk) ----------------
// R4: old k_w0f_wcp had 5 blocks; block 4 read 4 MB alone -> 164 us @ 25 GB/s (1 CU).
__global__ void k_pre1(const float* __restrict__ W0, const float* __restrict__ Wf,
                       const float* __restrict__ Wc, const float* __restrict__ Wproj,
                       float* __restrict__ W0f, float* __restrict__ Wcp, float* __restrict__ CQ) {
    int blk = blockIdx.x, tid = threadIdx.x;
    if (blk < 1024) {
        const float* row = W0 + (size_t)blk*1024;
        float a = 0.f;
        for (int j = tid; j < 1024; j += 256) a += row[j] * Wf[j];
        a = blockReduceSum(a);
        if (tid == 0) W0f[blk] = a;
    } else if (blk < 1040) {
        int r = blk - 1024; int c = r >> 2, is = r & 3; int i = is*256 + tid;
        float a = 0.f;
        for (int j = 0; j < 512; ++j) a += Wc[c*512 + j] * Wproj[(size_t)(512 + j)*1024 + i];
        Wcp[c*1024 + i] = a;
    } else {
        int r = blk - 1040;
        CQ[r*256 + tid] = 0.f;
    }
}

// ---------------- stage B: v (2048 blk) + CQ j-split atomic (256 blk) ----------------
__global__ void k_pre2(Ptrs4f W, const float* __restrict__ WV1, const float* __restrict__ WV2,
                       const float* __restrict__ W0f, const float* __restrict__ Wcp,
                       float* __restrict__ v, float* __restrict__ CQ) {
    int blk = blockIdx.x, tid = threadIdx.x;
    if (blk < 2048) {
        int h = blk >> 10, i = blk & 1023;
        const float* WV = h ? WV2 : WV1;
        const float* wf = W0f + h*512;
        float a = 0.f;
        for (int aa = tid; aa < 512; aa += 256) a += WV[(size_t)i*512 + aa] * wf[aa];
        a = blockReduceSum(a);
        if (tid == 0) v[h*1024 + i] = a;
    } else {
        int r = blk - 2048;              // 0..255
        int ns = r & 1, wc = (r >> 1) & 15, jc = r >> 5;   // jc 0..7
        int w = wc & 3, c = wc >> 2; int n = ns*256 + tid;
        const float* Ww = W.p[w];
        float a = 0.f;
        for (int j = jc*128; j < jc*128 + 128; ++j) a += Wcp[c*1024 + j] * Ww[(size_t)j*512 + n];
        atomicAdd(&CQ[(size_t)(w*4 + c)*512 + n], a);
    }
}

// ---------------- MFMA GEMM: C[M,N] = alpha * A[M,K] @ B[N,K]^T (bf16 in) ----------------
__device__ __forceinline__ void cstore(float* p, float v) { *p = v; }
__device__ __forceinline__ void cstore(u16* p, float v)   { *p = f2bf(v); }

template<typename CT, bool STATS>
__device__ __forceinline__ void mfma_gemm(const u16* __restrict__ A, const u16* __restrict__ B,
                                          CT* __restrict__ C, int M, int N, int K, float alpha,
                                          float* __restrict__ Pm, float* __restrict__ Pd) {
    __shared__ u16 As[128*40];   // row stride 40 (80B): 2-way bank conflict only (free, m136)
    __shared__ u16 Bs[128*40];
    const int tid = threadIdx.x;
    const int wave = tid >> 6, lane = tid & 63;
    const int quad = lane >> 4, l16 = lane & 15;
    const int m0 = blockIdx.y*128, n0 = blockIdx.x*128;
    const int wm = (wave >> 1)*64, wn = (wave & 1)*64;
    const int srow = tid >> 2, schunk = tid & 3;
    f32x4 acc[4][4] = {};

    for (int k0 = 0; k0 < K; k0 += 32) {
        #pragma unroll
        for (int rr = 0; rr < 2; ++rr) {
            int row = srow + rr*64;
            int gm = m0 + row, gn = n0 + row;
            uint4 av = make_uint4(0,0,0,0), bv = make_uint4(0,0,0,0);
            if (gm < M) av = *(const uint4*)(A + (size_t)gm*K + k0 + schunk*8);
            if (gn < N) bv = *(const uint4*)(B + (size_t)gn*K + k0 + schunk*8);
            *(uint4*)(As + row*40 + schunk*8) = av;
            *(uint4*)(Bs + row*40 + schunk*8) = bv;
        }
        __syncthreads();
        s16x8 af[4], bf[4];
        #pragma unroll
        for (int i = 0; i < 4; ++i) af[i] = *(const s16x8*)(As + (wm + i*16 + l16)*40 + quad*8);
        #pragma unroll
        for (int j = 0; j < 4; ++j) bf[j] = *(const s16x8*)(Bs + (wn + j*16 + l16)*40 + quad*8);
        #pragma unroll
        for (int i = 0; i < 4; ++i)
            #pragma unroll
            for (int j = 0; j < 4; ++j)
                acc[i][j] = __builtin_amdgcn_mfma_f32_16x16x32_bf16(af[i], bf[j], acc[i][j], 0, 0, 0);
        __syncthreads();
    }
    // C/D layout: col = lane&15, row = quad*4 + reg  [measured m89/m91]
    #pragma unroll
    for (int i = 0; i < 4; ++i) {
        #pragma unroll
        for (int r = 0; r < 4; ++r) {
            int gm = m0 + wm + i*16 + quad*4 + r;
            if (gm < M) {
                #pragma unroll
                for (int j = 0; j < 4; ++j) {
                    int gn = n0 + wn + j*16 + l16;
                    cstore(C + (size_t)gm*N + gn, acc[i][j][r] * alpha);
                }
            }
        }
    }
    if (STATS) {
        // per-tile column (query-axis) stats: this wave covers cols wn+j*16+l16, rows wm..wm+63
        __shared__ float sMax[4][64];
        __shared__ float sSum[4][64];
        #pragma unroll
        for (int j = 0; j < 4; ++j) {
            float mx = -3.4e38f;
            #pragma unroll
            for (int i = 0; i < 4; ++i)
                #pragma unroll
                for (int r = 0; r < 4; ++r) mx = fmaxf(mx, acc[i][j][r] * alpha);
            mx = fmaxf(mx, __shfl_xor(mx, 16, 64));
            mx = fmaxf(mx, __shfl_xor(mx, 32, 64));    // column max over 64 rows
            float sm = 0.f;
            #pragma unroll
            for (int i = 0; i < 4; ++i)
                #pragma unroll
                for (int r = 0; r < 4; ++r) sm += expf(acc[i][j][r] * alpha - mx);
            sm += __shfl_xor(sm, 16, 64);
            sm += __shfl_xor(sm, 32, 64);
            if (quad == 0) { sMax[wave][j*16 + l16] = mx; sSum[wave][j*16 + l16] = sm; }
        }
        __syncthreads();
        if (tid < 128) {
            int c = tid;
            int w0 = (c < 64) ? 0 : 1, ci = c & 63;
            float m0v = sMax[w0][ci],     s0 = sSum[w0][ci];
            float m1v = sMax[w0 + 2][ci], s1 = sSum[w0 + 2][ci];
            float mm = fmaxf(m0v, m1v);
            float ss = s0 * expf(m0v - mm) + s1 * expf(m1v - mm);
            Pm[n0 + c] = mm;     // caller pre-offsets Pm/Pd by (b*8 + mt)*1024
            Pd[n0 + c] = ss;
        }
    }
}

__global__ __launch_bounds__(256) void k_g_T16(const u16* __restrict__ E16, const u16* __restrict__ WpT, u16* __restrict__ T16) {
    int f = blockIdx.z;
    mfma_gemm<u16,false>(E16 + (size_t)f*1000*128, WpT + (size_t)f*1024*128, T16 + (size_t)f*1000*1024, 1000, 1024, 128, 1.f, nullptr, nullptr);
}
__global__ __launch_bounds__(256) void k_g_TQK(const u16* __restrict__ T16, const u16* __restrict__ Wt, u16* __restrict__ TQK16) {
    int f = blockIdx.z >> 2;
    mfma_gemm<u16,false>(T16 + (size_t)f*1000*1024, Wt + (size_t)(blockIdx.z & 3)*512*1024,
                   TQK16 + (size_t)blockIdx.z*1000*512, 1000, 512, 1024, 1.f, nullptr, nullptr);
}
__global__ __launch_bounds__(256) void k_g_PEQ(const u16* __restrict__ PE16, const u16* __restrict__ Wt, u16* __restrict__ PEQ16) {
    mfma_gemm<u16,false>(PE16, Wt + (size_t)blockIdx.z*512*1024, PEQ16 + (size_t)blockIdx.z*1024*512, 1024, 512, 1024, 1.f, nullptr, nullptr);
}
// scores + fused per-tile column stats
__global__ __launch_bounds__(256) void k_g_S(const u16* __restrict__ Q, const u16* __restrict__ K,
                                             float* __restrict__ Sb, float alpha,
                                             float* __restrict__ Pm, float* __restrict__ Pd, int b0) {
    size_t b = blockIdx.z;
    size_t po = ((b0 + b)*8 + blockIdx.y)*1024;
    mfma_gemm<float,true>(Q + b*SS*AT, K + b*SS*AT, Sb + b*SS*SS, 1024, 1024, 512, alpha, Pm + po, Pd + po);
}

// ---------------- small dot products: Ut, pu, cu ----------------
__global__ void k_dots(const u16* __restrict__ T16, const float* __restrict__ PE,
                       const float* __restrict__ Wcp, const float* __restrict__ v,
                       float* __restrict__ Ut, float* __restrict__ pu, float* __restrict__ cu) {
    int id = blockIdx.x;
    float p;
    if (id < 8000) {
        int f = id / 2000, rem = id % 2000, h = rem / 1000, r = rem % 1000;
        float4 a = ld4bf(T16 + ((size_t)f*1000 + r)*1024 + threadIdx.x*4);
        float4 b = ld4(v + h*1024 + threadIdx.x*4);
        p = a.x*b.x + a.y*b.y + a.z*b.z + a.w*b.w;
        p = blockReduceSum(p);
        if (threadIdx.x == 0) Ut[(size_t)(f*2 + h)*1000 + r] = p;
    } else if (id < 10048) {
        int tq = id - 8000; int h = tq >> 10, s = tq & 1023;
        float4 a = ld4(PE + (size_t)s*1024 + threadIdx.x*4);
        float4 b = ld4(v + h*1024 + threadIdx.x*4);
        p = a.x*b.x + a.y*b.y + a.z*b.z + a.w*b.w;
        p = blockReduceSum(p);
        if (threadIdx.x == 0) pu[h*1024 + s] = p;
    } else {
        int tq = id - 10048; int h = tq >> 2, c = tq & 3;
        float4 a = ld4(Wcp + c*1024 + threadIdx.x*4);
        float4 b = ld4(v + h*1024 + threadIdx.x*4);
        p = a.x*b.x + a.y*b.y + a.z*b.z + a.w*b.w;
        p = blockReduceSum(p);
        if (threadIdx.x == 0) cu[h*4 + c] = p;
    }
}

// ---------------- gather for head h: Q,K rows (bf16) + u ----------------
__global__ void k_gather(const int* __restrict__ cate, const float* __restrict__ cont,
                         const u16* __restrict__ TQK, const float* __restrict__ CQ,
                         const u16* __restrict__ PEQ, const float* __restrict__ Ut,
                         const float* __restrict__ cu, const float* __restrict__ pu,
                         u16* __restrict__ Qh, u16* __restrict__ Kh,
                         float* __restrict__ u, int h) {
    size_t t = blockIdx.x; int s = (int)(t & 1023);
    int tid = threadIdx.x;
    int c0 = cate[t*4+0], c1 = cate[t*4+1], c2 = cate[t*4+2], c3 = cate[t*4+3];
    float cv0 = cont[t*4+0], cv1 = cont[t*4+1];
    float cv2 = cont[t*4+2], cv3 = cont[t*4+3];
    int n = tid*2;
    #pragma unroll
    for (int e = 0; e < 2; ++e) {
        int w = 2*h + e;
        const u16* t0 = TQK + ((size_t)(0  + w)*1000 + c0)*512;
        const u16* t1 = TQK + ((size_t)(4  + w)*1000 + c1)*512;
        const u16* t2 = TQK + ((size_t)(8  + w)*1000 + c2)*512;
        const u16* t3 = TQK + ((size_t)(12 + w)*1000 + c3)*512;
        const u16* pq = PEQ + ((size_t)w*1024 + s)*512;
        const float* cq = CQ + (size_t)w*2048;
        float x0 = bf2f(t0[n]) + bf2f(t1[n]) + bf2f(t2[n]) + bf2f(t3[n]) + bf2f(pq[n])
                 + cv0*cq[n] + cv1*cq[512+n] + cv2*cq[1024+n] + cv3*cq[1536+n];
        float x1 = bf2f(t0[n+1]) + bf2f(t1[n+1]) + bf2f(t2[n+1]) + bf2f(t3[n+1]) + bf2f(pq[n+1])
                 + cv0*cq[n+1] + cv1*cq[512+n+1] + cv2*cq[1024+n+1] + cv3*cq[1536+n+1];
        u16* op = (e ? Kh : Qh) + t*512;
        unsigned int pack = ((unsigned int)f2bf(x1) << 16) | f2bf(x0);
        *(unsigned int*)(op + n) = pack;
    }
    if (tid == 0) {
        float uu = pu[h*1024 + s]
                 + Ut[(0*2 + h)*1000 + c0] + Ut[(1*2 + h)*1000 + c1]
                 + Ut[(2*2 + h)*1000 + c2] + Ut[(3*2 + h)*1000 + c3]
                 + cv0*cu[h*4+0] + cv1*cu[h*4+1] + cv2*cu[h*4+2] + cv3*cu[h*4+3];
        u[(size_t)h*NT + t] = uu;
    }
}

// ---------------- combine per-tile stats (8 m-tiles) ----------------
__global__ void k_stats_combine(const float* __restrict__ Pm, const float* __restrict__ Pd,
                                const float* __restrict__ u, float* __restrict__ m,
                                float* __restrict__ w, int b0) {
    int idx = b0*1024 + blockIdx.x*256 + threadIdx.x;   // b*1024 + k
    int b = idx >> 10, k = idx & 1023;
    float mx = -3.4e38f;
    #pragma unroll
    for (int mt = 0; mt < 8; ++mt) mx = fmaxf(mx, Pm[((size_t)b*8 + mt)*1024 + k]);
    float dd = 0.f;
    #pragma unroll
    for (int mt = 0; mt < 8; ++mt) dd += Pd[((size_t)b*8 + mt)*1024 + k]
                                       * expf(Pm[((size_t)b*8 + mt)*1024 + k] - mx);
    m[idx] = mx;
    w[idx] = u[idx] / dd;
}

// ---------------- logits ----------------
__global__ void k_logit(const float* __restrict__ Sb, const float* __restrict__ m,
                        const float* __restrict__ w, float* __restrict__ logits,
                        int b0, int init) {
    size_t tl = blockIdx.x;                  // local row within chunk
    size_t tabs = (size_t)b0*1024 + tl;
    int b = (int)(tabs >> 10);
    const float* row = Sb + tl*1024;
    const float* mb = m + (size_t)b*1024;
    const float* wb = w + (size_t)b*1024;
    float acc = 0.f;
    for (int k = threadIdx.x; k < 1024; k += 256) acc += expf(row[k] - mb[k]) * wb[k];
    acc = blockReduceSum(acc);
    if (threadIdx.x == 0) { if (init) logits[tabs] = acc; else logits[tabs] += acc; }
}

// Output is FLOAT32 (reference returns fp32; harness reads fp32).
__global__ void k_final(const float* __restrict__ logits, float* __restrict__ out) {
    int t = blockIdx.x*256 + threadIdx.x;
    float x = logits[t];
    out[t] = 1.f / (1.f + expf(-x));
}

extern "C" void kernel_launch(void* const* d_in, const int* in_sizes, int n_in,
                              void* d_out, int out_size, void* d_ws, size_t ws_size,
                              hipStream_t stream) {
    const int*   cate = (const int*)d_in[0];
    const float* cont = (const float*)d_in[1];
    Ptrs4f E; E.p[0] = (const float*)d_in[4]; E.p[1] = (const float*)d_in[5];
              E.p[2] = (const float*)d_in[6]; E.p[3] = (const float*)d_in[7];
    const float* Wc    = (const float*)d_in[8];
    const float* Wproj = (const float*)d_in[9];
    Ptrs4f W; W.p[0] = (const float*)d_in[10];  // WQ1
              W.p[1] = (const float*)d_in[11];  // WK1
              W.p[2] = (const float*)d_in[13];  // WQ2
              W.p[3] = (const float*)d_in[14];  // WK2
    const float* WV1 = (const float*)d_in[12];
    const float* WV2 = (const float*)d_in[15];
    const float* W0  = (const float*)d_in[16];
    const float* Wf  = (const float*)d_in[17];

    char* base = (char*)d_ws;
    size_t off = 0;
    auto alloc = [&](size_t bytes) { void* p = base + off; off += (bytes + 255) & ~(size_t)255; return p; };
    float* PE    = (float*)alloc(1048576ull*4);
    u16*   PE16  = (u16*)  alloc(1048576ull*2);
    u16*   E16   = (u16*)  alloc(4ull*1000*128*2);
    u16*   Wt    = (u16*)  alloc(4ull*512*1024*2);
    u16*   WpT   = (u16*)  alloc(4ull*1024*128*2);
    u16*   T16   = (u16*)  alloc(4ull*1000*1024*2);
    u16*   TQK16 = (u16*)  alloc(16ull*1000*512*2);
    u16*   PEQ16 = (u16*)  alloc(4ull*1024*512*2);
    float* Wcp   = (float*)alloc(4*1024*4);
    float* W0f   = (float*)alloc(1024*4);
    float* vv    = (float*)alloc(2*1024*4);
    float* CQ    = (float*)alloc(16*512*4);
    float* Ut    = (float*)alloc(8*1000*4);
    float* cu    = (float*)alloc(8*4);
    float* pu    = (float*)alloc(2*1024*4);
    float* ubuf  = (float*)alloc(2ull*NT*4);
    u16*   Qh    = (u16*)  alloc((size_t)NT*512*2);
    u16*   Kh    = (u16*)  alloc((size_t)NT*512*2);
    float* Pm    = (float*)alloc(32ull*8*1024*4);
    float* Pd    = (float*)alloc(32ull*8*1024*4);
    float* mbuf  = (float*)alloc(32*1024*4);
    float* wbuf  = (float*)alloc(32*1024*4);
    float* logits= (float*)alloc((size_t)NT*4);
    size_t sChunkBytes = (size_t)SS*SS*4;
    size_t remain = (ws_size > off) ? (ws_size - off) : 0;
    int NB = (int)(remain / sChunkBytes);
    if (NB > 32) NB = 32;
    if (NB < 1) NB = 1;
    float* Sbuf = (float*)(base + off);

    const float alpha = 0.044194173824159216f;   // 1/sqrt(512)

    k_pe<<<1024, 512, 0, stream>>>(PE);
    k_cvt<<<4096, 256, 0, stream>>>(PE, PE16, 1048576);
    k_cvtE<<<dim3(500, 4), 256, 0, stream>>>(E, E16);
    k_transp<<<dim3(16, 32, 4), dim3(32, 32), 0, stream>>>(W, Wt, 1024, 512);
    Ptrs4f Wp4; for (int f = 0; f < 4; ++f) Wp4.p[f] = Wproj + (size_t)f*128*1024;
    k_transp<<<dim3(32, 4, 4), dim3(32, 32), 0, stream>>>(Wp4, WpT, 128, 1024);
    k_pre1<<<1072, 256, 0, stream>>>(W0, Wf, Wc, Wproj, W0f, Wcp, CQ);
    k_pre2<<<2304, 256, 0, stream>>>(W, WV1, WV2, W0f, Wcp, vv, CQ);
    k_g_T16<<<dim3(8, 8, 4), 256, 0, stream>>>(E16, WpT, T16);
    k_g_TQK<<<dim3(4, 8, 16), 256, 0, stream>>>(T16, Wt, TQK16);
    k_g_PEQ<<<dim3(4, 8, 4), 256, 0, stream>>>(PE16, Wt, PEQ16);
    k_dots<<<10056, 256, 0, stream>>>(T16, PE, Wcp, vv, Ut, pu, cu);

    for (int h = 0; h < 2; ++h) {
        k_gather<<<NT, 256, 0, stream>>>(cate, cont, TQK16, CQ, PEQ16, Ut, cu, pu, Qh, Kh, ubuf, h);
        for (int b0 = 0; b0 < 32; b0 += NB) {
            int nb = (32 - b0 < NB) ? (32 - b0) : NB;
            k_g_S<<<dim3(8, 8, nb), 256, 0, stream>>>(Qh + (size_t)b0*SS*AT, Kh + (size_t)b0*SS*AT, Sbuf, alpha, Pm, Pd, b0);
            k_stats_combine<<<nb*4, 256, 0, stream>>>(Pm, Pd, ubuf + (size_t)h*NT, mbuf, wbuf, b0);
            k_logit<<<nb*SS, 256, 0, stream>>>(Sbuf, mbuf, wbuf, logits, b0, h == 0 ? 1 : 0);
        }
    }
    k_final<<<128, 256, 0, stream>>>(logits, (float*)d_out);
}

// Round 6
// 526.020 us; speedup vs baseline: 1.6731x; 1.1078x over previous
//
#include <hip/hip_runtime.h>
#include <hip/hip_bf16.h>
#include <math.h>

#define BB    32
#define SS    1024
#define HID   1024
#define AT    512
#define NVOC  1000
#define NT    (BB*SS)

typedef unsigned short u16;
typedef __attribute__((ext_vector_type(8))) short s16x8;   // 8 bf16 (4 VGPRs)
typedef __attribute__((ext_vector_type(4))) float f32x4;   // MFMA acc

__device__ __forceinline__ float bf2f(u16 u) {
    union { unsigned int i; float f; } x; x.i = ((unsigned int)u) << 16; return x.f;
}
__device__ __forceinline__ u16 f2bf(float f) {
    union { float f; unsigned int i; } u; u.f = f;
    unsigned int r = u.i + 0x7fffu + ((u.i >> 16) & 1u);
    return (u16)(r >> 16);
}
__device__ __forceinline__ float4 ld4(const float* p) { return *(const float4*)p; }
__device__ __forceinline__ float4 ld4bf(const u16* p) {
    ushort4 v = *(const ushort4*)p;
    return make_float4(bf2f(v.x), bf2f(v.y), bf2f(v.z), bf2f(v.w));
}

// async global->LDS, 16B per lane; LDS dest = uniform base + lane*16 [m97]
__device__ __forceinline__ void gld16(const u16* g, u16* l) {
    __builtin_amdgcn_global_load_lds(
        (const __attribute__((address_space(1))) unsigned int*)g,
        (__attribute__((address_space(3))) unsigned int*)l,
        16, 0, 0);
}

struct Ptrs4f { const float* p[4]; };

__device__ __forceinline__ float blockReduceSum(float x) {
    #pragma unroll
    for (int off = 32; off > 0; off >>= 1) x += __shfl_down(x, off, 64);
    __shared__ float tmp[4];
    int lane = threadIdx.x & 63, wid = threadIdx.x >> 6;
    if (lane == 0) tmp[wid] = x;
    __syncthreads();
    if (threadIdx.x == 0) x = tmp[0] + tmp[1] + tmp[2] + tmp[3];
    return x; // valid on thread 0 only
}

// ---------------- PE table (fp32) + bf16 copy ----------------
__global__ void k_pe(float* __restrict__ PE) {
    int s = blockIdx.x, i = threadIdx.x;               // 512 threads
    float denom = powf(10000.f, (2.f * (float)i) / 1024.f);
    float ang = (float)s / denom;
    PE[(long)s*1024 + 2*i]     = sinf(ang);
    PE[(long)s*1024 + 2*i + 1] = cosf(ang);
}
__global__ void k_cvt(const float* __restrict__ in, u16* __restrict__ out, int n) {
    int i = blockIdx.x*256 + threadIdx.x;
    if (i < n) out[i] = f2bf(in[i]);
}
__global__ void k_cvtE(Ptrs4f E, u16* __restrict__ out) {
    int f = blockIdx.y;
    int i = blockIdx.x*256 + threadIdx.x;               // 0..127999
    if (i < 128000) out[(size_t)f*128000 + i] = f2bf(E.p[f][i]);
}

// ---------------- transpose fp32 -> bf16: out[c][r] = in[r][c] ----------------
__global__ void k_transp(Ptrs4f src, u16* __restrict__ dst, int R, int C) {
    const float* in = src.p[blockIdx.z];
    u16* out = dst + (size_t)blockIdx.z * R * C;
    int r0 = blockIdx.y*32, c0 = blockIdx.x*32;
    __shared__ float tt[32][33];
    tt[threadIdx.y][threadIdx.x] = in[(size_t)(r0 + threadIdx.y)*C + c0 + threadIdx.x];
    __syncthreads();
    out[(size_t)(c0 + threadIdx.y)*R + r0 + threadIdx.x] = f2bf(tt[threadIdx.x][threadIdx.y]);
}

// ---------------- stage A: W0f rows (1024 blk) + Wcp (16 blk) + CQ zero (32 blk) ----------------
__global__ void k_pre1(const float* __restrict__ W0, const float* __restrict__ Wf,
                       const float* __restrict__ Wc, const float* __restrict__ Wproj,
                       float* __restrict__ W0f, float* __restrict__ Wcp, float* __restrict__ CQ) {
    int blk = blockIdx.x, tid = threadIdx.x;
    if (blk < 1024) {
        const float* row = W0 + (size_t)blk*1024;
        float a = 0.f;
        for (int j = tid; j < 1024; j += 256) a += row[j] * Wf[j];
        a = blockReduceSum(a);
        if (tid == 0) W0f[blk] = a;
    } else if (blk < 1040) {
        int r = blk - 1024; int c = r >> 2, is = r & 3; int i = is*256 + tid;
        float a = 0.f;
        for (int j = 0; j < 512; ++j) a += Wc[c*512 + j] * Wproj[(size_t)(512 + j)*1024 + i];
        Wcp[c*1024 + i] = a;
    } else {
        int r = blk - 1040;
        CQ[r*256 + tid] = 0.f;
    }
}

// ---------------- stage B: v (2048 blk) + CQ j-split atomic (256 blk) ----------------
__global__ void k_pre2(Ptrs4f W, const float* __restrict__ WV1, const float* __restrict__ WV2,
                       const float* __restrict__ W0f, const float* __restrict__ Wcp,
                       float* __restrict__ v, float* __restrict__ CQ) {
    int blk = blockIdx.x, tid = threadIdx.x;
    if (blk < 2048) {
        int h = blk >> 10, i = blk & 1023;
        const float* WV = h ? WV2 : WV1;
        const float* wf = W0f + h*512;
        float a = 0.f;
        for (int aa = tid; aa < 512; aa += 256) a += WV[(size_t)i*512 + aa] * wf[aa];
        a = blockReduceSum(a);
        if (tid == 0) v[h*1024 + i] = a;
    } else {
        int r = blk - 2048;              // 0..255
        int ns = r & 1, wc = (r >> 1) & 15, jc = r >> 5;   // jc 0..7
        int w = wc & 3, c = wc >> 2; int n = ns*256 + tid;
        const float* Ww = W.p[w];
        float a = 0.f;
        for (int j = jc*128; j < jc*128 + 128; ++j) a += Wcp[c*1024 + j] * Ww[(size_t)j*512 + n];
        atomicAdd(&CQ[(size_t)(w*4 + c)*512 + n], a);
    }
}

// ---------------- MFMA GEMM: C[M,N] = alpha * A[M,K] @ B[N,K]^T (bf16 in) ----------------
// m97-style: global_load_lds width 16 staging into unpadded 128x32 LDS tiles.
__device__ __forceinline__ void cstore(float* p, float v) { *p = v; }
__device__ __forceinline__ void cstore(u16* p, float v)   { *p = f2bf(v); }

template<typename CT, bool STATS>
__device__ __forceinline__ void mfma_gemm(const u16* __restrict__ A, const u16* __restrict__ B,
                                          CT* __restrict__ C, int M, int N, int K, float alpha,
                                          float* __restrict__ Pm, float* __restrict__ Pd) {
    __shared__ u16 As[128*32];   // unpadded: required by global_load_lds lane-contiguous layout
    __shared__ u16 Bs[128*32];
    const int tid = threadIdx.x;
    const int wave = tid >> 6, lane = tid & 63;
    const int quad = lane >> 4, l16 = lane & 15;
    const int m0 = blockIdx.y*128, n0 = blockIdx.x*128;
    const int wm = (wave >> 1)*64, wn = (wave & 1)*64;
    const int lrow = lane >> 2, lc8 = (lane & 3)*8;
    f32x4 acc[4][4] = {};

    for (int k0 = 0; k0 < K; k0 += 32) {
        #pragma unroll
        for (int p = 0; p < 2; ++p) {
            int r0 = wave*32 + p*16;
            gld16(A + (size_t)(m0 + r0 + lrow)*K + k0 + lc8, As + r0*32);
            gld16(B + (size_t)(n0 + r0 + lrow)*K + k0 + lc8, Bs + r0*32);
        }
        __syncthreads();
        s16x8 af[4], bf[4];
        #pragma unroll
        for (int i = 0; i < 4; ++i) af[i] = *(const s16x8*)(As + (wm + i*16 + l16)*32 + quad*8);
        #pragma unroll
        for (int j = 0; j < 4; ++j) bf[j] = *(const s16x8*)(Bs + (wn + j*16 + l16)*32 + quad*8);
        #pragma unroll
        for (int i = 0; i < 4; ++i)
            #pragma unroll
            for (int j = 0; j < 4; ++j)
                acc[i][j] = __builtin_amdgcn_mfma_f32_16x16x32_bf16(af[i], bf[j], acc[i][j], 0, 0, 0);
        __syncthreads();
    }
    // C/D layout: col = lane&15, row = quad*4 + reg  [measured m89/m91]
    #pragma unroll
    for (int i = 0; i < 4; ++i) {
        #pragma unroll
        for (int r = 0; r < 4; ++r) {
            int gm = m0 + wm + i*16 + quad*4 + r;
            if (gm < M) {
                #pragma unroll
                for (int j = 0; j < 4; ++j) {
                    int gn = n0 + wn + j*16 + l16;
                    cstore(C + (size_t)gm*N + gn, acc[i][j][r] * alpha);
                }
            }
        }
    }
    if (STATS) {
        // per-tile column (query-axis) stats; waves w and w+2 share cols, split rows
        __shared__ float sMax[4][64];
        __shared__ float sSum[4][64];
        #pragma unroll
        for (int j = 0; j < 4; ++j) {
            float mx = -3.4e38f;
            #pragma unroll
            for (int i = 0; i < 4; ++i)
                #pragma unroll
                for (int r = 0; r < 4; ++r) mx = fmaxf(mx, acc[i][j][r] * alpha);
            mx = fmaxf(mx, __shfl_xor(mx, 16, 64));
            mx = fmaxf(mx, __shfl_xor(mx, 32, 64));    // column max over this wave's 64 rows
            float sm = 0.f;
            #pragma unroll
            for (int i = 0; i < 4; ++i)
                #pragma unroll
                for (int r = 0; r < 4; ++r) sm += expf(acc[i][j][r] * alpha - mx);
            sm += __shfl_xor(sm, 16, 64);
            sm += __shfl_xor(sm, 32, 64);
            if (quad == 0) { sMax[wave][j*16 + l16] = mx; sSum[wave][j*16 + l16] = sm; }
        }
        __syncthreads();
        if (tid < 128) {
            int c = tid;
            int w0 = (c < 64) ? 0 : 1, ci = c & 63;
            float m0v = sMax[w0][ci],     s0 = sSum[w0][ci];
            float m1v = sMax[w0 + 2][ci], s1 = sSum[w0 + 2][ci];
            float mm = fmaxf(m0v, m1v);
            float ss = s0 * expf(m0v - mm) + s1 * expf(m1v - mm);
            Pm[n0 + c] = mm;     // caller pre-offsets Pm/Pd by (b*8 + mt)*1024
            Pd[n0 + c] = ss;
        }
    }
}

__global__ __launch_bounds__(256) void k_g_T16(const u16* __restrict__ E16, const u16* __restrict__ WpT, u16* __restrict__ T16) {
    int f = blockIdx.z;
    mfma_gemm<u16,false>(E16 + (size_t)f*1000*128, WpT + (size_t)f*1024*128, T16 + (size_t)f*1000*1024, 1000, 1024, 128, 1.f, nullptr, nullptr);
}
__global__ __launch_bounds__(256) void k_g_TQK(const u16* __restrict__ T16, const u16* __restrict__ Wt, u16* __restrict__ TQK16) {
    int f = blockIdx.z >> 2;
    mfma_gemm<u16,false>(T16 + (size_t)f*1000*1024, Wt + (size_t)(blockIdx.z & 3)*512*1024,
                   TQK16 + (size_t)blockIdx.z*1000*512, 1000, 512, 1024, 1.f, nullptr, nullptr);
}
__global__ __launch_bounds__(256) void k_g_PEQ(const u16* __restrict__ PE16, const u16* __restrict__ Wt, u16* __restrict__ PEQ16) {
    mfma_gemm<u16,false>(PE16, Wt + (size_t)blockIdx.z*512*1024, PEQ16 + (size_t)blockIdx.z*1024*512, 1024, 512, 1024, 1.f, nullptr, nullptr);
}
// scores + fused per-tile column stats
__global__ __launch_bounds__(256) void k_g_S(const u16* __restrict__ Q, const u16* __restrict__ K,
                                             float* __restrict__ Sb, float alpha,
                                             float* __restrict__ Pm, float* __restrict__ Pd, int b0) {
    size_t b = blockIdx.z;
    size_t po = ((b0 + b)*8 + blockIdx.y)*1024;
    mfma_gemm<float,true>(Q + b*SS*AT, K + b*SS*AT, Sb + b*SS*SS, 1024, 1024, 512, alpha, Pm + po, Pd + po);
}

// ---------------- small dot products: Ut, pu, cu ----------------
__global__ void k_dots(const u16* __restrict__ T16, const float* __restrict__ PE,
                       const float* __restrict__ Wcp, const float* __restrict__ v,
                       float* __restrict__ Ut, float* __restrict__ pu, float* __restrict__ cu) {
    int id = blockIdx.x;
    float p;
    if (id < 8000) {
        int f = id / 2000, rem = id % 2000, h = rem / 1000, r = rem % 1000;
        float4 a = ld4bf(T16 + ((size_t)f*1000 + r)*1024 + threadIdx.x*4);
        float4 b = ld4(v + h*1024 + threadIdx.x*4);
        p = a.x*b.x + a.y*b.y + a.z*b.z + a.w*b.w;
        p = blockReduceSum(p);
        if (threadIdx.x == 0) Ut[(size_t)(f*2 + h)*1000 + r] = p;
    } else if (id < 10048) {
        int tq = id - 8000; int h = tq >> 10, s = tq & 1023;
        float4 a = ld4(PE + (size_t)s*1024 + threadIdx.x*4);
        float4 b = ld4(v + h*1024 + threadIdx.x*4);
        p = a.x*b.x + a.y*b.y + a.z*b.z + a.w*b.w;
        p = blockReduceSum(p);
        if (threadIdx.x == 0) pu[h*1024 + s] = p;
    } else {
        int tq = id - 10048; int h = tq >> 2, c = tq & 3;
        float4 a = ld4(Wcp + c*1024 + threadIdx.x*4);
        float4 b = ld4(v + h*1024 + threadIdx.x*4);
        p = a.x*b.x + a.y*b.y + a.z*b.z + a.w*b.w;
        p = blockReduceSum(p);
        if (threadIdx.x == 0) cu[h*4 + c] = p;
    }
}

// ---------------- gather for head h: Q,K rows (bf16) + u ----------------
__global__ void k_gather(const int* __restrict__ cate, const float* __restrict__ cont,
                         const u16* __restrict__ TQK, const float* __restrict__ CQ,
                         const u16* __restrict__ PEQ, const float* __restrict__ Ut,
                         const float* __restrict__ cu, const float* __restrict__ pu,
                         u16* __restrict__ Qh, u16* __restrict__ Kh,
                         float* __restrict__ u, int h) {
    size_t t = blockIdx.x; int s = (int)(t & 1023);
    int tid = threadIdx.x;
    int c0 = cate[t*4+0], c1 = cate[t*4+1], c2 = cate[t*4+2], c3 = cate[t*4+3];
    float cv0 = cont[t*4+0], cv1 = cont[t*4+1];
    float cv2 = cont[t*4+2], cv3 = cont[t*4+3];
    int n = tid*2;
    #pragma unroll
    for (int e = 0; e < 2; ++e) {
        int w = 2*h + e;
        const u16* t0 = TQK + ((size_t)(0  + w)*1000 + c0)*512;
        const u16* t1 = TQK + ((size_t)(4  + w)*1000 + c1)*512;
        const u16* t2 = TQK + ((size_t)(8  + w)*1000 + c2)*512;
        const u16* t3 = TQK + ((size_t)(12 + w)*1000 + c3)*512;
        const u16* pq = PEQ + ((size_t)w*1024 + s)*512;
        const float* cq = CQ + (size_t)w*2048;
        float x0 = bf2f(t0[n]) + bf2f(t1[n]) + bf2f(t2[n]) + bf2f(t3[n]) + bf2f(pq[n])
                 + cv0*cq[n] + cv1*cq[512+n] + cv2*cq[1024+n] + cv3*cq[1536+n];
        float x1 = bf2f(t0[n+1]) + bf2f(t1[n+1]) + bf2f(t2[n+1]) + bf2f(t3[n+1]) + bf2f(pq[n+1])
                 + cv0*cq[n+1] + cv1*cq[512+n+1] + cv2*cq[1024+n+1] + cv3*cq[1536+n+1];
        u16* op = (e ? Kh : Qh) + t*512;
        unsigned int pack = ((unsigned int)f2bf(x1) << 16) | f2bf(x0);
        *(unsigned int*)(op + n) = pack;
    }
    if (tid == 0) {
        float uu = pu[h*1024 + s]
                 + Ut[(0*2 + h)*1000 + c0] + Ut[(1*2 + h)*1000 + c1]
                 + Ut[(2*2 + h)*1000 + c2] + Ut[(3*2 + h)*1000 + c3]
                 + cv0*cu[h*4+0] + cv1*cu[h*4+1] + cv2*cu[h*4+2] + cv3*cu[h*4+3];
        u[(size_t)h*NT + t] = uu;
    }
}

// ---------------- combine per-tile stats (8 m-tiles) ----------------
__global__ void k_stats_combine(const float* __restrict__ Pm, const float* __restrict__ Pd,
                                const float* __restrict__ u, float* __restrict__ m,
                                float* __restrict__ w, int b0) {
    int idx = b0*1024 + blockIdx.x*256 + threadIdx.x;   // b*1024 + k
    int b = idx >> 10, k = idx & 1023;
    float mx = -3.4e38f;
    #pragma unroll
    for (int mt = 0; mt < 8; ++mt) mx = fmaxf(mx, Pm[((size_t)b*8 + mt)*1024 + k]);
    float dd = 0.f;
    #pragma unroll
    for (int mt = 0; mt < 8; ++mt) dd += Pd[((size_t)b*8 + mt)*1024 + k]
                                       * expf(Pm[((size_t)b*8 + mt)*1024 + k] - mx);
    m[idx] = mx;
    w[idx] = u[idx] / dd;
}

// ---------------- logits ----------------
__global__ void k_logit(const float* __restrict__ Sb, const float* __restrict__ m,
                        const float* __restrict__ w, float* __restrict__ logits,
                        int b0, int init) {
    size_t tl = blockIdx.x;                  // local row within chunk
    size_t tabs = (size_t)b0*1024 + tl;
    int b = (int)(tabs >> 10);
    const float* row = Sb + tl*1024;
    const float* mb = m + (size_t)b*1024;
    const float* wb = w + (size_t)b*1024;
    float acc = 0.f;
    for (int k = threadIdx.x; k < 1024; k += 256) acc += expf(row[k] - mb[k]) * wb[k];
    acc = blockReduceSum(acc);
    if (threadIdx.x == 0) { if (init) logits[tabs] = acc; else logits[tabs] += acc; }
}

// Output is FLOAT32 (reference returns fp32; harness reads fp32).
__global__ void k_final(const float* __restrict__ logits, float* __restrict__ out) {
    int t = blockIdx.x*256 + threadIdx.x;
    float x = logits[t];
    out[t] = 1.f / (1.f + expf(-x));
}

extern "C" void kernel_launch(void* const* d_in, const int* in_sizes, int n_in,
                              void* d_out, int out_size, void* d_ws, size_t ws_size,
                              hipStream_t stream) {
    const int*   cate = (const int*)d_in[0];
    const float* cont = (const float*)d_in[1];
    Ptrs4f E; E.p[0] = (const float*)d_in[4]; E.p[1] = (const float*)d_in[5];
              E.p[2] = (const float*)d_in[6]; E.p[3] = (const float*)d_in[7];
    const float* Wc    = (const float*)d_in[8];
    const float* Wproj = (const float*)d_in[9];
    Ptrs4f W; W.p[0] = (const float*)d_in[10];  // WQ1
              W.p[1] = (const float*)d_in[11];  // WK1
              W.p[2] = (const float*)d_in[13];  // WQ2
              W.p[3] = (const float*)d_in[14];  // WK2
    const float* WV1 = (const float*)d_in[12];
    const float* WV2 = (const float*)d_in[15];
    const float* W0  = (const float*)d_in[16];
    const float* Wf  = (const float*)d_in[17];

    char* base = (char*)d_ws;
    size_t off = 0;
    auto alloc = [&](size_t bytes) { void* p = base + off; off += (bytes + 255) & ~(size_t)255; return p; };
    float* PE    = (float*)alloc(1048576ull*4);
    u16*   PE16  = (u16*)  alloc(1048576ull*2);
    u16*   E16   = (u16*)  alloc(4ull*1000*128*2);
    u16*   Wt    = (u16*)  alloc(4ull*512*1024*2);
    u16*   WpT   = (u16*)  alloc(4ull*1024*128*2);
    u16*   T16   = (u16*)  alloc(4ull*1000*1024*2);
    u16*   TQK16 = (u16*)  alloc(16ull*1000*512*2);
    u16*   PEQ16 = (u16*)  alloc(4ull*1024*512*2);
    float* Wcp   = (float*)alloc(4*1024*4);
    float* W0f   = (float*)alloc(1024*4);
    float* vv    = (float*)alloc(2*1024*4);
    float* CQ    = (float*)alloc(16*512*4);
    float* Ut    = (float*)alloc(8*1000*4);
    float* cu    = (float*)alloc(8*4);
    float* pu    = (float*)alloc(2*1024*4);
    float* ubuf  = (float*)alloc(2ull*NT*4);
    u16*   Qh    = (u16*)  alloc((size_t)NT*512*2);
    u16*   Kh    = (u16*)  alloc((size_t)NT*512*2);
    float* Pm    = (float*)alloc(32ull*8*1024*4);
    float* Pd    = (float*)alloc(32ull*8*1024*4);
    float* mbuf  = (float*)alloc(32*1024*4);
    float* wbuf  = (float*)alloc(32*1024*4);
    float* logits= (float*)alloc((size_t)NT*4);
    size_t sChunkBytes = (size_t)SS*SS*4;
    size_t remain = (ws_size > off) ? (ws_size - off) : 0;
    int NB = (int)(remain / sChunkBytes);
    if (NB > 32) NB = 32;
    if (NB < 1) NB = 1;
    float* Sbuf = (float*)(base + off);

    const float alpha = 0.044194173824159216f;   // 1/sqrt(512)

    k_pe<<<1024, 512, 0, stream>>>(PE);
    k_cvt<<<4096, 256, 0, stream>>>(PE, PE16, 1048576);
    k_cvtE<<<dim3(500, 4), 256, 0, stream>>>(E, E16);
    k_transp<<<dim3(16, 32, 4), dim3(32, 32), 0, stream>>>(W, Wt, 1024, 512);
    Ptrs4f Wp4; for (int f = 0; f < 4; ++f) Wp4.p[f] = Wproj + (size_t)f*128*1024;
    k_transp<<<dim3(32, 4, 4), dim3(32, 32), 0, stream>>>(Wp4, WpT, 128, 1024);
    k_pre1<<<1072, 256, 0, stream>>>(W0, Wf, Wc, Wproj, W0f, Wcp, CQ);
    k_pre2<<<2304, 256, 0, stream>>>(W, WV1, WV2, W0f, Wcp, vv, CQ);
    k_g_T16<<<dim3(8, 8, 4), 256, 0, stream>>>(E16, WpT, T16);
    k_g_TQK<<<dim3(4, 8, 16), 256, 0, stream>>>(T16, Wt, TQK16);
    k_g_PEQ<<<dim3(4, 8, 4), 256, 0, stream>>>(PE16, Wt, PEQ16);
    k_dots<<<10056, 256, 0, stream>>>(T16, PE, Wcp, vv, Ut, pu, cu);

    for (int h = 0; h < 2; ++h) {
        k_gather<<<NT, 256, 0, stream>>>(cate, cont, TQK16, CQ, PEQ16, Ut, cu, pu, Qh, Kh, ubuf, h);
        for (int b0 = 0; b0 < 32; b0 += NB) {
            int nb = (32 - b0 < NB) ? (32 - b0) : NB;
            k_g_S<<<dim3(8, 8, nb), 256, 0, stream>>>(Qh + (size_t)b0*SS*AT, Kh + (size_t)b0*SS*AT, Sbuf, alpha, Pm, Pd, b0);
            k_stats_combine<<<nb*4, 256, 0, stream>>>(Pm, Pd, ubuf + (size_t)h*NT, mbuf, wbuf, b0);
            k_logit<<<nb*SS, 256, 0, stream>>>(Sbuf, mbuf, wbuf, logits, b0, h == 0 ? 1 : 0);
        }
    }
    k_final<<<128, 256, 0, stream>>>(logits, (float*)d_out);
}

// Round 7
// 465.402 us; speedup vs baseline: 1.8910x; 1.1302x over previous
//
#include <hip/hip_runtime.h>
#include <hip/hip_bf16.h>
#include <math.h>

#define BB    32
#define SS    1024
#define HID   1024
#define AT    512
#define NVOC  1000
#define NT    (BB*SS)

typedef unsigned short u16;
typedef __attribute__((ext_vector_type(8))) short s16x8;   // 8 bf16 (4 VGPRs)
typedef __attribute__((ext_vector_type(4))) float f32x4;   // MFMA acc

__device__ __forceinline__ float bf2f(u16 u) {
    union { unsigned int i; float f; } x; x.i = ((unsigned int)u) << 16; return x.f;
}
__device__ __forceinline__ u16 f2bf(float f) {
    union { float f; unsigned int i; } u; u.f = f;
    unsigned int r = u.i + 0x7fffu + ((u.i >> 16) & 1u);
    return (u16)(r >> 16);
}
__device__ __forceinline__ float4 ld4(const float* p) { return *(const float4*)p; }
__device__ __forceinline__ float4 ld4bf(const u16* p) {
    ushort4 v = *(const ushort4*)p;
    return make_float4(bf2f(v.x), bf2f(v.y), bf2f(v.z), bf2f(v.w));
}

// async global->LDS, 16B per lane; LDS dest = uniform base + lane*16 [m97]
__device__ __forceinline__ void gld16(const u16* g, u16* l) {
    __builtin_amdgcn_global_load_lds(
        (const __attribute__((address_space(1))) unsigned int*)g,
        (__attribute__((address_space(3))) unsigned int*)l,
        16, 0, 0);
}

struct Ptrs4f { const float* p[4]; };

__device__ __forceinline__ float blockReduceSum(float x) {
    #pragma unroll
    for (int off = 32; off > 0; off >>= 1) x += __shfl_down(x, off, 64);
    __shared__ float tmp[4];
    int lane = threadIdx.x & 63, wid = threadIdx.x >> 6;
    if (lane == 0) tmp[wid] = x;
    __syncthreads();
    if (threadIdx.x == 0) x = tmp[0] + tmp[1] + tmp[2] + tmp[3];
    return x; // valid on thread 0 only
}

// ---------------- PE table (fp32) + bf16 copy ----------------
__global__ void k_pe(float* __restrict__ PE) {
    int s = blockIdx.x, i = threadIdx.x;               // 512 threads
    const float l2_10000 = 13.287712379549449f;        // log2(10000)
    float denom = exp2f((2.f * (float)i / 1024.f) * l2_10000);
    float ang = (float)s / denom;
    PE[(long)s*1024 + 2*i]     = sinf(ang);
    PE[(long)s*1024 + 2*i + 1] = cosf(ang);
}
__global__ void k_cvt(const float* __restrict__ in, u16* __restrict__ out, int n) {
    int i = blockIdx.x*256 + threadIdx.x;
    if (i < n) out[i] = f2bf(in[i]);
}
__global__ void k_cvtE(Ptrs4f E, u16* __restrict__ out) {
    int f = blockIdx.y;
    int i = blockIdx.x*256 + threadIdx.x;               // 0..127999
    if (i < 128000) out[(size_t)f*128000 + i] = f2bf(E.p[f][i]);
}

// ---------------- transpose fp32 -> bf16: out[c][r] = in[r][c] ----------------
__global__ void k_transp(Ptrs4f src, u16* __restrict__ dst, int R, int C) {
    const float* in = src.p[blockIdx.z];
    u16* out = dst + (size_t)blockIdx.z * R * C;
    int r0 = blockIdx.y*32, c0 = blockIdx.x*32;
    __shared__ float tt[32][33];
    tt[threadIdx.y][threadIdx.x] = in[(size_t)(r0 + threadIdx.y)*C + c0 + threadIdx.x];
    __syncthreads();
    out[(size_t)(c0 + threadIdx.y)*R + r0 + threadIdx.x] = f2bf(tt[threadIdx.x][threadIdx.y]);
}

// ---------------- stage A: W0f rows (1024 blk) + Wcp (16 blk) + CQ zero (32 blk) ----------------
__global__ void k_pre1(const float* __restrict__ W0, const float* __restrict__ Wf,
                       const float* __restrict__ Wc, const float* __restrict__ Wproj,
                       float* __restrict__ W0f, float* __restrict__ Wcp, float* __restrict__ CQ) {
    int blk = blockIdx.x, tid = threadIdx.x;
    if (blk < 1024) {
        const float* row = W0 + (size_t)blk*1024;
        float a = 0.f;
        for (int j = tid; j < 1024; j += 256) a += row[j] * Wf[j];
        a = blockReduceSum(a);
        if (tid == 0) W0f[blk] = a;
    } else if (blk < 1040) {
        int r = blk - 1024; int c = r >> 2, is = r & 3; int i = is*256 + tid;
        float a = 0.f;
        for (int j = 0; j < 512; ++j) a += Wc[c*512 + j] * Wproj[(size_t)(512 + j)*1024 + i];
        Wcp[c*1024 + i] = a;
    } else {
        int r = blk - 1040;
        CQ[r*256 + tid] = 0.f;
    }
}

// ---------------- stage B: v (2048 blk) + CQ j-split atomic (256 blk) ----------------
__global__ void k_pre2(Ptrs4f W, const float* __restrict__ WV1, const float* __restrict__ WV2,
                       const float* __restrict__ W0f, const float* __restrict__ Wcp,
                       float* __restrict__ v, float* __restrict__ CQ) {
    int blk = blockIdx.x, tid = threadIdx.x;
    if (blk < 2048) {
        int h = blk >> 10, i = blk & 1023;
        const float* WV = h ? WV2 : WV1;
        const float* wf = W0f + h*512;
        float a = 0.f;
        for (int aa = tid; aa < 512; aa += 256) a += WV[(size_t)i*512 + aa] * wf[aa];
        a = blockReduceSum(a);
        if (tid == 0) v[h*1024 + i] = a;
    } else {
        int r = blk - 2048;              // 0..255
        int ns = r & 1, wc = (r >> 1) & 15, jc = r >> 5;   // jc 0..7
        int w = wc & 3, c = wc >> 2; int n = ns*256 + tid;
        const float* Ww = W.p[w];
        float a = 0.f;
        for (int j = jc*128; j < jc*128 + 128; ++j) a += Wcp[c*1024 + j] * Ww[(size_t)j*512 + n];
        atomicAdd(&CQ[(size_t)(w*4 + c)*512 + n], a);
    }
}

// ---------------- MFMA GEMM: C[M,N] = alpha * A[M,K] @ B[N,K]^T (bf16 in) ----------------
// m97-style: global_load_lds width 16 staging into unpadded 128x32 LDS tiles.
// STATS: round S to bf16 FIRST, compute column stats from the rounded values so
// numerator (k_logit) and denominator use identical quantized scores.
__device__ __forceinline__ void cstore(float* p, float v) { *p = v; }
__device__ __forceinline__ void cstore(u16* p, float v)   { *p = f2bf(v); }

template<typename CT, bool STATS>
__device__ __forceinline__ void mfma_gemm(const u16* __restrict__ A, const u16* __restrict__ B,
                                          CT* __restrict__ C, int M, int N, int K, float alpha,
                                          float* __restrict__ Pm, float* __restrict__ Pd) {
    __shared__ u16 As[128*32];   // unpadded: required by global_load_lds lane-contiguous layout
    __shared__ u16 Bs[128*32];
    const int tid = threadIdx.x;
    const int wave = tid >> 6, lane = tid & 63;
    const int quad = lane >> 4, l16 = lane & 15;
    const int m0 = blockIdx.y*128, n0 = blockIdx.x*128;
    const int wm = (wave >> 1)*64, wn = (wave & 1)*64;
    const int lrow = lane >> 2, lc8 = (lane & 3)*8;
    f32x4 acc[4][4] = {};

    for (int k0 = 0; k0 < K; k0 += 32) {
        #pragma unroll
        for (int p = 0; p < 2; ++p) {
            int r0 = wave*32 + p*16;
            gld16(A + (size_t)(m0 + r0 + lrow)*K + k0 + lc8, As + r0*32);
            gld16(B + (size_t)(n0 + r0 + lrow)*K + k0 + lc8, Bs + r0*32);
        }
        __syncthreads();
        s16x8 af[4], bf[4];
        #pragma unroll
        for (int i = 0; i < 4; ++i) af[i] = *(const s16x8*)(As + (wm + i*16 + l16)*32 + quad*8);
        #pragma unroll
        for (int j = 0; j < 4; ++j) bf[j] = *(const s16x8*)(Bs + (wn + j*16 + l16)*32 + quad*8);
        #pragma unroll
        for (int i = 0; i < 4; ++i)
            #pragma unroll
            for (int j = 0; j < 4; ++j)
                acc[i][j] = __builtin_amdgcn_mfma_f32_16x16x32_bf16(af[i], bf[j], acc[i][j], 0, 0, 0);
        __syncthreads();
    }
    if (STATS) {
        // quantize in place so store + stats use identical values
        #pragma unroll
        for (int i = 0; i < 4; ++i)
            #pragma unroll
            for (int j = 0; j < 4; ++j)
                #pragma unroll
                for (int r = 0; r < 4; ++r) acc[i][j][r] = bf2f(f2bf(acc[i][j][r] * alpha));
        alpha = 1.f;
    }
    // C/D layout: col = lane&15, row = quad*4 + reg  [measured m89/m91]
    #pragma unroll
    for (int i = 0; i < 4; ++i) {
        #pragma unroll
        for (int r = 0; r < 4; ++r) {
            int gm = m0 + wm + i*16 + quad*4 + r;
            if (gm < M) {
                #pragma unroll
                for (int j = 0; j < 4; ++j) {
                    int gn = n0 + wn + j*16 + l16;
                    cstore(C + (size_t)gm*N + gn, acc[i][j][r] * alpha);
                }
            }
        }
    }
    if (STATS) {
        // per-tile column (query-axis) stats; waves w and w+2 share cols, split rows
        __shared__ float sMax[4][64];
        __shared__ float sSum[4][64];
        #pragma unroll
        for (int j = 0; j < 4; ++j) {
            float mx = -3.4e38f;
            #pragma unroll
            for (int i = 0; i < 4; ++i)
                #pragma unroll
                for (int r = 0; r < 4; ++r) mx = fmaxf(mx, acc[i][j][r]);
            mx = fmaxf(mx, __shfl_xor(mx, 16, 64));
            mx = fmaxf(mx, __shfl_xor(mx, 32, 64));    // column max over this wave's 64 rows
            float sm = 0.f;
            #pragma unroll
            for (int i = 0; i < 4; ++i)
                #pragma unroll
                for (int r = 0; r < 4; ++r) sm += expf(acc[i][j][r] - mx);
            sm += __shfl_xor(sm, 16, 64);
            sm += __shfl_xor(sm, 32, 64);
            if (quad == 0) { sMax[wave][j*16 + l16] = mx; sSum[wave][j*16 + l16] = sm; }
        }
        __syncthreads();
        if (tid < 128) {
            int c = tid;
            int w0 = (c < 64) ? 0 : 1, ci = c & 63;
            float m0v = sMax[w0][ci],     s0 = sSum[w0][ci];
            float m1v = sMax[w0 + 2][ci], s1 = sSum[w0 + 2][ci];
            float mm = fmaxf(m0v, m1v);
            float ss = s0 * expf(m0v - mm) + s1 * expf(m1v - mm);
            Pm[n0 + c] = mm;     // caller pre-offsets Pm/Pd by (b*8 + mt)*1024
            Pd[n0 + c] = ss;
        }
    }
}

__global__ __launch_bounds__(256) void k_g_T16(const u16* __restrict__ E16, const u16* __restrict__ WpT, u16* __restrict__ T16) {
    int f = blockIdx.z;
    mfma_gemm<u16,false>(E16 + (size_t)f*1000*128, WpT + (size_t)f*1024*128, T16 + (size_t)f*1000*1024, 1000, 1024, 128, 1.f, nullptr, nullptr);
}
__global__ __launch_bounds__(256) void k_g_TQK(const u16* __restrict__ T16, const u16* __restrict__ Wt, u16* __restrict__ TQK16) {
    int f = blockIdx.z >> 2;
    mfma_gemm<u16,false>(T16 + (size_t)f*1000*1024, Wt + (size_t)(blockIdx.z & 3)*512*1024,
                   TQK16 + (size_t)blockIdx.z*1000*512, 1000, 512, 1024, 1.f, nullptr, nullptr);
}
__global__ __launch_bounds__(256) void k_g_PEQ(const u16* __restrict__ PE16, const u16* __restrict__ Wt, u16* __restrict__ PEQ16) {
    mfma_gemm<u16,false>(PE16, Wt + (size_t)blockIdx.z*512*1024, PEQ16 + (size_t)blockIdx.z*1024*512, 1024, 512, 1024, 1.f, nullptr, nullptr);
}
// scores (bf16 out) + fused per-tile column stats
__global__ __launch_bounds__(256) void k_g_S(const u16* __restrict__ Q, const u16* __restrict__ K,
                                             u16* __restrict__ Sb, float alpha,
                                             float* __restrict__ Pm, float* __restrict__ Pd, int b0) {
    size_t b = blockIdx.z;
    size_t po = ((b0 + b)*8 + blockIdx.y)*1024;
    mfma_gemm<u16,true>(Q + b*SS*AT, K + b*SS*AT, Sb + b*SS*SS, 1024, 1024, 512, alpha, Pm + po, Pd + po);
}

// ---------------- small dot products: Ut, pu, cu ----------------
__global__ void k_dots(const u16* __restrict__ T16, const float* __restrict__ PE,
                       const float* __restrict__ Wcp, const float* __restrict__ v,
                       float* __restrict__ Ut, float* __restrict__ pu, float* __restrict__ cu) {
    int id = blockIdx.x;
    float p;
    if (id < 8000) {
        int f = id / 2000, rem = id % 2000, h = rem / 1000, r = rem % 1000;
        float4 a = ld4bf(T16 + ((size_t)f*1000 + r)*1024 + threadIdx.x*4);
        float4 b = ld4(v + h*1024 + threadIdx.x*4);
        p = a.x*b.x + a.y*b.y + a.z*b.z + a.w*b.w;
        p = blockReduceSum(p);
        if (threadIdx.x == 0) Ut[(size_t)(f*2 + h)*1000 + r] = p;
    } else if (id < 10048) {
        int tq = id - 8000; int h = tq >> 10, s = tq & 1023;
        float4 a = ld4(PE + (size_t)s*1024 + threadIdx.x*4);
        float4 b = ld4(v + h*1024 + threadIdx.x*4);
        p = a.x*b.x + a.y*b.y + a.z*b.z + a.w*b.w;
        p = blockReduceSum(p);
        if (threadIdx.x == 0) pu[h*1024 + s] = p;
    } else {
        int tq = id - 10048; int h = tq >> 2, c = tq & 3;
        float4 a = ld4(Wcp + c*1024 + threadIdx.x*4);
        float4 b = ld4(v + h*1024 + threadIdx.x*4);
        p = a.x*b.x + a.y*b.y + a.z*b.z + a.w*b.w;
        p = blockReduceSum(p);
        if (threadIdx.x == 0) cu[h*4 + c] = p;
    }
}

// ---------------- gather for head h: 2 tokens/block, 8 bf16/thread ----------------
__device__ __forceinline__ void unpack8(uint4 v, float* x) {
    x[0] = bf2f((u16)(v.x & 0xffff)); x[1] = bf2f((u16)(v.x >> 16));
    x[2] = bf2f((u16)(v.y & 0xffff)); x[3] = bf2f((u16)(v.y >> 16));
    x[4] = bf2f((u16)(v.z & 0xffff)); x[5] = bf2f((u16)(v.z >> 16));
    x[6] = bf2f((u16)(v.w & 0xffff)); x[7] = bf2f((u16)(v.w >> 16));
}

__global__ void k_gather(const int* __restrict__ cate, const float* __restrict__ cont,
                         const u16* __restrict__ TQK, const float* __restrict__ CQ,
                         const u16* __restrict__ PEQ, const float* __restrict__ Ut,
                         const float* __restrict__ cu, const float* __restrict__ pu,
                         u16* __restrict__ Qh, u16* __restrict__ Kh,
                         float* __restrict__ u, int h) {
    int tid = threadIdx.x;
    size_t t = (size_t)blockIdx.x*2 + (tid >> 7);
    int r = tid & 127;
    int s = (int)(t & 1023);
    int4 cc = *(const int4*)(cate + t*4);
    float4 cv = ld4(cont + t*4);
    int e = r >> 6;                 // 0=Q, 1=K
    int w = 2*h + e;
    int n = (r & 63)*8;
    const u16* t0 = TQK + ((size_t)(0  + w)*1000 + cc.x)*512 + n;
    const u16* t1 = TQK + ((size_t)(4  + w)*1000 + cc.y)*512 + n;
    const u16* t2 = TQK + ((size_t)(8  + w)*1000 + cc.z)*512 + n;
    const u16* t3 = TQK + ((size_t)(12 + w)*1000 + cc.w)*512 + n;
    const u16* pq = PEQ + ((size_t)w*1024 + s)*512 + n;
    const float* cq = CQ + (size_t)w*2048 + n;
    float a0[8], a1[8], a2[8], a3[8], ap[8];
    unpack8(*(const uint4*)t0, a0); unpack8(*(const uint4*)t1, a1);
    unpack8(*(const uint4*)t2, a2); unpack8(*(const uint4*)t3, a3);
    unpack8(*(const uint4*)pq, ap);
    unsigned int pack[4];
    #pragma unroll
    for (int jp = 0; jp < 4; ++jp) {
        float x0, x1;
        #pragma unroll
        for (int half = 0; half < 2; ++half) {
            int j = jp*2 + half;
            float x = a0[j] + a1[j] + a2[j] + a3[j] + ap[j]
                    + cv.x*cq[j] + cv.y*cq[512+j] + cv.z*cq[1024+j] + cv.w*cq[1536+j];
            if (half == 0) x0 = x; else x1 = x;
        }
        pack[jp] = ((unsigned int)f2bf(x1) << 16) | f2bf(x0);
    }
    u16* op = (e ? Kh : Qh) + t*512 + n;
    *(uint4*)op = make_uint4(pack[0], pack[1], pack[2], pack[3]);
    if (r == 0) {
        float uu = pu[h*1024 + s]
                 + Ut[(0*2 + h)*1000 + cc.x] + Ut[(1*2 + h)*1000 + cc.y]
                 + Ut[(2*2 + h)*1000 + cc.z] + Ut[(3*2 + h)*1000 + cc.w]
                 + cv.x*cu[h*4+0] + cv.y*cu[h*4+1] + cv.z*cu[h*4+2] + cv.w*cu[h*4+3];
        u[(size_t)h*NT + t] = uu;
    }
}

// ---------------- combine per-tile stats (8 m-tiles) ----------------
__global__ void k_stats_combine(const float* __restrict__ Pm, const float* __restrict__ Pd,
                                const float* __restrict__ u, float* __restrict__ m,
                                float* __restrict__ w, int b0) {
    int idx = b0*1024 + blockIdx.x*256 + threadIdx.x;   // b*1024 + k
    int b = idx >> 10, k = idx & 1023;
    float mx = -3.4e38f;
    #pragma unroll
    for (int mt = 0; mt < 8; ++mt) mx = fmaxf(mx, Pm[((size_t)b*8 + mt)*1024 + k]);
    float dd = 0.f;
    #pragma unroll
    for (int mt = 0; mt < 8; ++mt) dd += Pd[((size_t)b*8 + mt)*1024 + k]
                                       * expf(Pm[((size_t)b*8 + mt)*1024 + k] - mx);
    m[idx] = mx;
    w[idx] = u[idx] / dd;
}

// ---------------- logits (S is bf16) ----------------
__global__ void k_logit(const u16* __restrict__ Sb, const float* __restrict__ m,
                        const float* __restrict__ w, float* __restrict__ logits,
                        int b0, int init) {
    size_t tl = blockIdx.x;                  // local row within chunk
    size_t tabs = (size_t)b0*1024 + tl;
    int b = (int)(tabs >> 10);
    const u16* row = Sb + tl*1024;
    const float* mb = m + (size_t)b*1024;
    const float* wb = w + (size_t)b*1024;
    int k = threadIdx.x*4;
    float4 s = ld4bf(row + k);
    float4 mm = ld4(mb + k);
    float4 ww = ld4(wb + k);
    float acc = expf(s.x - mm.x)*ww.x + expf(s.y - mm.y)*ww.y
              + expf(s.z - mm.z)*ww.z + expf(s.w - mm.w)*ww.w;
    acc = blockReduceSum(acc);
    if (threadIdx.x == 0) { if (init) logits[tabs] = acc; else logits[tabs] += acc; }
}

// Output is FLOAT32 (reference returns fp32; harness reads fp32).
__global__ void k_final(const float* __restrict__ logits, float* __restrict__ out) {
    int t = blockIdx.x*256 + threadIdx.x;
    float x = logits[t];
    out[t] = 1.f / (1.f + expf(-x));
}

extern "C" void kernel_launch(void* const* d_in, const int* in_sizes, int n_in,
                              void* d_out, int out_size, void* d_ws, size_t ws_size,
                              hipStream_t stream) {
    const int*   cate = (const int*)d_in[0];
    const float* cont = (const float*)d_in[1];
    Ptrs4f E; E.p[0] = (const float*)d_in[4]; E.p[1] = (const float*)d_in[5];
              E.p[2] = (const float*)d_in[6]; E.p[3] = (const float*)d_in[7];
    const float* Wc    = (const float*)d_in[8];
    const float* Wproj = (const float*)d_in[9];
    Ptrs4f W; W.p[0] = (const float*)d_in[10];  // WQ1
              W.p[1] = (const float*)d_in[11];  // WK1
              W.p[2] = (const float*)d_in[13];  // WQ2
              W.p[3] = (const float*)d_in[14];  // WK2
    const float* WV1 = (const float*)d_in[12];
    const float* WV2 = (const float*)d_in[15];
    const float* W0  = (const float*)d_in[16];
    const float* Wf  = (const float*)d_in[17];

    char* base = (char*)d_ws;
    size_t off = 0;
    auto alloc = [&](size_t bytes) { void* p = base + off; off += (bytes + 255) & ~(size_t)255; return p; };
    float* PE    = (float*)alloc(1048576ull*4);
    u16*   PE16  = (u16*)  alloc(1048576ull*2);
    u16*   E16   = (u16*)  alloc(4ull*1000*128*2);
    u16*   Wt    = (u16*)  alloc(4ull*512*1024*2);
    u16*   WpT   = (u16*)  alloc(4ull*1024*128*2);
    u16*   T16   = (u16*)  alloc(4ull*1000*1024*2);
    u16*   TQK16 = (u16*)  alloc(16ull*1000*512*2);
    u16*   PEQ16 = (u16*)  alloc(4ull*1024*512*2);
    float* Wcp   = (float*)alloc(4*1024*4);
    float* W0f   = (float*)alloc(1024*4);
    float* vv    = (float*)alloc(2*1024*4);
    float* CQ    = (float*)alloc(16*512*4);
    float* Ut    = (float*)alloc(8*1000*4);
    float* cu    = (float*)alloc(8*4);
    float* pu    = (float*)alloc(2*1024*4);
    float* ubuf  = (float*)alloc(2ull*NT*4);
    u16*   Qh    = (u16*)  alloc((size_t)NT*512*2);
    u16*   Kh    = (u16*)  alloc((size_t)NT*512*2);
    float* Pm    = (float*)alloc(32ull*8*1024*4);
    float* Pd    = (float*)alloc(32ull*8*1024*4);
    float* mbuf  = (float*)alloc(32*1024*4);
    float* wbuf  = (float*)alloc(32*1024*4);
    float* logits= (float*)alloc((size_t)NT*4);
    size_t sChunkBytes = (size_t)SS*SS*2;     // bf16 S
    size_t remain = (ws_size > off) ? (ws_size - off) : 0;
    int NB = (int)(remain / sChunkBytes);
    if (NB > 32) NB = 32;
    if (NB < 1) NB = 1;
    u16* Sbuf = (u16*)(base + off);

    const float alpha = 0.044194173824159216f;   // 1/sqrt(512)

    k_pe<<<1024, 512, 0, stream>>>(PE);
    k_cvt<<<4096, 256, 0, stream>>>(PE, PE16, 1048576);
    k_cvtE<<<dim3(500, 4), 256, 0, stream>>>(E, E16);
    k_transp<<<dim3(16, 32, 4), dim3(32, 32), 0, stream>>>(W, Wt, 1024, 512);
    Ptrs4f Wp4; for (int f = 0; f < 4; ++f) Wp4.p[f] = Wproj + (size_t)f*128*1024;
    k_transp<<<dim3(32, 4, 4), dim3(32, 32), 0, stream>>>(Wp4, WpT, 128, 1024);
    k_pre1<<<1072, 256, 0, stream>>>(W0, Wf, Wc, Wproj, W0f, Wcp, CQ);
    k_pre2<<<2304, 256, 0, stream>>>(W, WV1, WV2, W0f, Wcp, vv, CQ);
    k_g_T16<<<dim3(8, 8, 4), 256, 0, stream>>>(E16, WpT, T16);
    k_g_TQK<<<dim3(4, 8, 16), 256, 0, stream>>>(T16, Wt, TQK16);
    k_g_PEQ<<<dim3(4, 8, 4), 256, 0, stream>>>(PE16, Wt, PEQ16);
    k_dots<<<10056, 256, 0, stream>>>(T16, PE, Wcp, vv, Ut, pu, cu);

    for (int h = 0; h < 2; ++h) {
        k_gather<<<NT/2, 256, 0, stream>>>(cate, cont, TQK16, CQ, PEQ16, Ut, cu, pu, Qh, Kh, ubuf, h);
        for (int b0 = 0; b0 < 32; b0 += NB) {
            int nb = (32 - b0 < NB) ? (32 - b0) : NB;
            k_g_S<<<dim3(8, 8, nb), 256, 0, stream>>>(Qh + (size_t)b0*SS*AT, Kh + (size_t)b0*SS*AT, Sbuf, alpha, Pm, Pd, b0);
            k_stats_combine<<<nb*4, 256, 0, stream>>>(Pm, Pd, ubuf + (size_t)h*NT, mbuf, wbuf, b0);
            k_logit<<<nb*SS, 256, 0, stream>>>(Sbuf, mbuf, wbuf, logits, b0, h == 0 ? 1 : 0);
        }
    }
    k_final<<<128, 256, 0, stream>>>(logits, (float*)d_out);
}

// Round 8
// 447.152 us; speedup vs baseline: 1.9682x; 1.0408x over previous
//
#include <hip/hip_runtime.h>
#include <hip/hip_bf16.h>
#include <math.h>

#define BB    32
#define SS    1024
#define HID   1024
#define AT    512
#define NVOC  1000
#define NT    (BB*SS)

typedef unsigned short u16;
typedef __attribute__((ext_vector_type(8))) short s16x8;   // 8 bf16 (4 VGPRs)
typedef __attribute__((ext_vector_type(4))) float f32x4;   // MFMA acc

__device__ __forceinline__ float bf2f(u16 u) {
    union { unsigned int i; float f; } x; x.i = ((unsigned int)u) << 16; return x.f;
}
__device__ __forceinline__ u16 f2bf(float f) {
    union { float f; unsigned int i; } u; u.f = f;
    unsigned int r = u.i + 0x7fffu + ((u.i >> 16) & 1u);
    return (u16)(r >> 16);
}
__device__ __forceinline__ float4 ld4(const float* p) { return *(const float4*)p; }
__device__ __forceinline__ float4 ld4bf(const u16* p) {
    ushort4 v = *(const ushort4*)p;
    return make_float4(bf2f(v.x), bf2f(v.y), bf2f(v.z), bf2f(v.w));
}

// async global->LDS, 16B per lane; LDS dest = uniform base + lane*16 [m97]
__device__ __forceinline__ void gld16(const u16* g, u16* l) {
    __builtin_amdgcn_global_load_lds(
        (const __attribute__((address_space(1))) unsigned int*)g,
        (__attribute__((address_space(3))) unsigned int*)l,
        16, 0, 0);
}

struct Ptrs4f { const float* p[4]; };

__device__ __forceinline__ float blockReduceSum(float x) {
    #pragma unroll
    for (int off = 32; off > 0; off >>= 1) x += __shfl_down(x, off, 64);
    __shared__ float tmp[4];
    int lane = threadIdx.x & 63, wid = threadIdx.x >> 6;
    if (lane == 0) tmp[wid] = x;
    __syncthreads();
    if (threadIdx.x == 0) x = tmp[0] + tmp[1] + tmp[2] + tmp[3];
    return x; // valid on thread 0 only
}

// ---------------- PE table, bf16 direct ----------------
__global__ void k_pe16(u16* __restrict__ PE16) {
    int s = blockIdx.x, i = threadIdx.x;               // 512 threads
    const float l2_10000 = 13.287712379549449f;        // log2(10000)
    float denom = exp2f((2.f * (float)i / 1024.f) * l2_10000);
    float ang = (float)s / denom;
    unsigned int pack = ((unsigned int)f2bf(cosf(ang)) << 16) | f2bf(sinf(ang));
    *(unsigned int*)(PE16 + (size_t)s*1024 + 2*i) = pack;
}
__global__ void k_cvtE(Ptrs4f E, u16* __restrict__ out) {
    int f = blockIdx.y;
    int i = blockIdx.x*256 + threadIdx.x;               // 0..127999
    if (i < 128000) out[(size_t)f*128000 + i] = f2bf(E.p[f][i]);
}

// ---------------- transpose fp32 -> bf16: out[c][r] = in[r][c] ----------------
__global__ void k_transp(Ptrs4f src, u16* __restrict__ dst, int R, int C) {
    const float* in = src.p[blockIdx.z];
    u16* out = dst + (size_t)blockIdx.z * R * C;
    int r0 = blockIdx.y*32, c0 = blockIdx.x*32;
    __shared__ float tt[32][33];
    tt[threadIdx.y][threadIdx.x] = in[(size_t)(r0 + threadIdx.y)*C + c0 + threadIdx.x];
    __syncthreads();
    out[(size_t)(c0 + threadIdx.y)*R + r0 + threadIdx.x] = f2bf(tt[threadIdx.x][threadIdx.y]);
}

// ---------------- stage A: W0f rows (1024 blk) + Wcp (16 blk) + CQ zero (32 blk) ----------------
__global__ void k_pre1(const float* __restrict__ W0, const float* __restrict__ Wf,
                       const float* __restrict__ Wc, const float* __restrict__ Wproj,
                       float* __restrict__ W0f, float* __restrict__ Wcp, float* __restrict__ CQ) {
    int blk = blockIdx.x, tid = threadIdx.x;
    if (blk < 1024) {
        const float* row = W0 + (size_t)blk*1024;
        float a = 0.f;
        for (int j = tid; j < 1024; j += 256) a += row[j] * Wf[j];
        a = blockReduceSum(a);
        if (tid == 0) W0f[blk] = a;
    } else if (blk < 1040) {
        int r = blk - 1024; int c = r >> 2, is = r & 3; int i = is*256 + tid;
        float a = 0.f;
        for (int j = 0; j < 512; ++j) a += Wc[c*512 + j] * Wproj[(size_t)(512 + j)*1024 + i];
        Wcp[c*1024 + i] = a;
    } else {
        int r = blk - 1040;
        CQ[r*256 + tid] = 0.f;
    }
}

// ---------------- stage B: v (2048 blk) + CQ j-split atomic (256 blk) ----------------
__global__ void k_pre2(Ptrs4f W, const float* __restrict__ WV1, const float* __restrict__ WV2,
                       const float* __restrict__ W0f, const float* __restrict__ Wcp,
                       float* __restrict__ v, float* __restrict__ CQ) {
    int blk = blockIdx.x, tid = threadIdx.x;
    if (blk < 2048) {
        int h = blk >> 10, i = blk & 1023;
        const float* WV = h ? WV2 : WV1;
        const float* wf = W0f + h*512;
        float a = 0.f;
        for (int aa = tid; aa < 512; aa += 256) a += WV[(size_t)i*512 + aa] * wf[aa];
        a = blockReduceSum(a);
        if (tid == 0) v[h*1024 + i] = a;
    } else {
        int r = blk - 2048;              // 0..255
        int ns = r & 1, wc = (r >> 1) & 15, jc = r >> 5;   // jc 0..7
        int w = wc & 3, c = wc >> 2; int n = ns*256 + tid;
        const float* Ww = W.p[w];
        float a = 0.f;
        for (int j = jc*128; j < jc*128 + 128; ++j) a += Wcp[c*1024 + j] * Ww[(size_t)j*512 + n];
        atomicAdd(&CQ[(size_t)(w*4 + c)*512 + n], a);
    }
}

// ---------------- MFMA GEMM: C[M,N] = alpha * A[M,K] @ B[N,K]^T (bf16 in) ----------------
// BK=64, global_load_lds width 16, XOR-swizzled k-chunks: LDS[row][c] holds global
// chunk c^(row&7) so ds_read_b128 fragment reads cover all 32 banks (2-way, free).
__device__ __forceinline__ void cstore(float* p, float v) { *p = v; }
__device__ __forceinline__ void cstore(u16* p, float v)   { *p = f2bf(v); }

template<typename CT, bool STATS>
__device__ __forceinline__ void mfma_gemm(const u16* __restrict__ A, const u16* __restrict__ B,
                                          CT* __restrict__ C, int M, int N, int K, float alpha,
                                          float* __restrict__ Pm, float* __restrict__ Pd,
                                          int m0, int n0) {
    __shared__ u16 As[128*64];
    __shared__ u16 Bs[128*64];
    const int tid = threadIdx.x;
    const int wave = tid >> 6, lane = tid & 63;
    const int quad = lane >> 4, l16 = lane & 15;
    const int wm = (wave >> 1)*64, wn = (wave & 1)*64;
    const int srow = lane >> 3;                 // 0..7 within the 8-row group
    const int scol = ((lane & 7) ^ srow) * 8;   // swizzled global k-chunk
    f32x4 acc[4][4] = {};

    for (int k0 = 0; k0 < K; k0 += 64) {
        #pragma unroll
        for (int p = 0; p < 4; ++p) {
            int rb = wave*32 + p*8;
            gld16(A + (size_t)(m0 + rb + srow)*K + k0 + scol, As + rb*64);
            gld16(B + (size_t)(n0 + rb + srow)*K + k0 + scol, Bs + rb*64);
        }
        __syncthreads();
        #pragma unroll
        for (int kk = 0; kk < 2; ++kk) {
            s16x8 af[4], bf[4];
            #pragma unroll
            for (int i = 0; i < 4; ++i) {
                int row = wm + i*16 + l16;
                af[i] = *(const s16x8*)(As + row*64 + (((kk*4 + quad) ^ (row & 7)) * 8));
            }
            #pragma unroll
            for (int j = 0; j < 4; ++j) {
                int row = wn + j*16 + l16;
                bf[j] = *(const s16x8*)(Bs + row*64 + (((kk*4 + quad) ^ (row & 7)) * 8));
            }
            #pragma unroll
            for (int i = 0; i < 4; ++i)
                #pragma unroll
                for (int j = 0; j < 4; ++j)
                    acc[i][j] = __builtin_amdgcn_mfma_f32_16x16x32_bf16(af[i], bf[j], acc[i][j], 0, 0, 0);
        }
        __syncthreads();
    }
    if (STATS) {
        // quantize in place so store + stats use identical values
        #pragma unroll
        for (int i = 0; i < 4; ++i)
            #pragma unroll
            for (int j = 0; j < 4; ++j)
                #pragma unroll
                for (int r = 0; r < 4; ++r) acc[i][j][r] = bf2f(f2bf(acc[i][j][r] * alpha));
        alpha = 1.f;
    }
    // C/D layout: col = lane&15, row = quad*4 + reg  [measured m89/m91]
    #pragma unroll
    for (int i = 0; i < 4; ++i) {
        #pragma unroll
        for (int r = 0; r < 4; ++r) {
            int gm = m0 + wm + i*16 + quad*4 + r;
            if (gm < M) {
                #pragma unroll
                for (int j = 0; j < 4; ++j) {
                    int gn = n0 + wn + j*16 + l16;
                    cstore(C + (size_t)gm*N + gn, acc[i][j][r] * alpha);
                }
            }
        }
    }
    if (STATS) {
        // per-tile column (query-axis) stats; waves w and w+2 share cols, split rows
        __shared__ float sMax[4][64];
        __shared__ float sSum[4][64];
        #pragma unroll
        for (int j = 0; j < 4; ++j) {
            float mx = -3.4e38f;
            #pragma unroll
            for (int i = 0; i < 4; ++i)
                #pragma unroll
                for (int r = 0; r < 4; ++r) mx = fmaxf(mx, acc[i][j][r]);
            mx = fmaxf(mx, __shfl_xor(mx, 16, 64));
            mx = fmaxf(mx, __shfl_xor(mx, 32, 64));    // column max over this wave's 64 rows
            float sm = 0.f;
            #pragma unroll
            for (int i = 0; i < 4; ++i)
                #pragma unroll
                for (int r = 0; r < 4; ++r) sm += expf(acc[i][j][r] - mx);
            sm += __shfl_xor(sm, 16, 64);
            sm += __shfl_xor(sm, 32, 64);
            if (quad == 0) { sMax[wave][j*16 + l16] = mx; sSum[wave][j*16 + l16] = sm; }
        }
        __syncthreads();
        if (tid < 128) {
            int c = tid;
            int w0 = (c < 64) ? 0 : 1, ci = c & 63;
            float m0v = sMax[w0][ci],     s0 = sSum[w0][ci];
            float m1v = sMax[w0 + 2][ci], s1 = sSum[w0 + 2][ci];
            float mm = fmaxf(m0v, m1v);
            float ss = s0 * expf(m0v - mm) + s1 * expf(m1v - mm);
            Pm[n0 + c] = mm;     // caller pre-offsets Pm/Pd by (b*8 + mtile)*1024
            Pd[n0 + c] = ss;
        }
    }
}

__global__ __launch_bounds__(256) void k_g_T16(const u16* __restrict__ E16, const u16* __restrict__ WpT, u16* __restrict__ T16) {
    int f = blockIdx.z;
    mfma_gemm<u16,false>(E16 + (size_t)f*1000*128, WpT + (size_t)f*1024*128, T16 + (size_t)f*1000*1024,
                         1000, 1024, 128, 1.f, nullptr, nullptr, blockIdx.y*128, blockIdx.x*128);
}
__global__ __launch_bounds__(256) void k_g_TQK(const u16* __restrict__ T16, const u16* __restrict__ Wt, u16* __restrict__ TQK16) {
    int f = blockIdx.z >> 2;
    mfma_gemm<u16,false>(T16 + (size_t)f*1000*1024, Wt + (size_t)(blockIdx.z & 3)*512*1024,
                   TQK16 + (size_t)blockIdx.z*1000*512, 1000, 512, 1024, 1.f, nullptr, nullptr,
                   blockIdx.y*128, blockIdx.x*128);
}
__global__ __launch_bounds__(256) void k_g_PEQ(const u16* __restrict__ PE16, const u16* __restrict__ Wt, u16* __restrict__ PEQ16) {
    mfma_gemm<u16,false>(PE16, Wt + (size_t)blockIdx.z*512*1024, PEQ16 + (size_t)blockIdx.z*1024*512,
                         1024, 512, 1024, 1.f, nullptr, nullptr, blockIdx.y*128, blockIdx.x*128);
}
// scores (bf16 out) + fused per-tile column stats; XCD-swizzled block map:
// blocks with equal (linear%8) form a 2x4 (n,m)-tile rectangle per batch.
__global__ __launch_bounds__(256) void k_g_S(const u16* __restrict__ Q, const u16* __restrict__ K,
                                             u16* __restrict__ Sb, float alpha,
                                             float* __restrict__ Pm, float* __restrict__ Pd, int b0) {
    size_t b = blockIdx.z;
    int bx = (blockIdx.x % 4)*2 + (blockIdx.y % 2);
    int by = (blockIdx.x / 4)*4 + (blockIdx.y / 2);
    size_t po = ((b0 + b)*8 + by)*1024;
    mfma_gemm<u16,true>(Q + b*SS*AT, K + b*SS*AT, Sb + b*SS*SS, 1024, 1024, 512, alpha,
                        Pm + po, Pd + po, by*128, bx*128);
}

// ---------------- small dot products: Ut, pu, cu ----------------
__global__ void k_dots(const u16* __restrict__ T16, const u16* __restrict__ PE16,
                       const float* __restrict__ Wcp, const float* __restrict__ v,
                       float* __restrict__ Ut, float* __restrict__ pu, float* __restrict__ cu) {
    int id = blockIdx.x;
    float p;
    if (id < 8000) {
        int f = id / 2000, rem = id % 2000, h = rem / 1000, r = rem % 1000;
        float4 a = ld4bf(T16 + ((size_t)f*1000 + r)*1024 + threadIdx.x*4);
        float4 b = ld4(v + h*1024 + threadIdx.x*4);
        p = a.x*b.x + a.y*b.y + a.z*b.z + a.w*b.w;
        p = blockReduceSum(p);
        if (threadIdx.x == 0) Ut[(size_t)(f*2 + h)*1000 + r] = p;
    } else if (id < 10048) {
        int tq = id - 8000; int h = tq >> 10, s = tq & 1023;
        float4 a = ld4bf(PE16 + (size_t)s*1024 + threadIdx.x*4);
        float4 b = ld4(v + h*1024 + threadIdx.x*4);
        p = a.x*b.x + a.y*b.y + a.z*b.z + a.w*b.w;
        p = blockReduceSum(p);
        if (threadIdx.x == 0) pu[h*1024 + s] = p;
    } else {
        int tq = id - 10048; int h = tq >> 2, c = tq & 3;
        float4 a = ld4(Wcp + c*1024 + threadIdx.x*4);
        float4 b = ld4(v + h*1024 + threadIdx.x*4);
        p = a.x*b.x + a.y*b.y + a.z*b.z + a.w*b.w;
        p = blockReduceSum(p);
        if (threadIdx.x == 0) cu[h*4 + c] = p;
    }
}

// ---------------- gather for head h: 2 tokens/block, 8 bf16/thread ----------------
__device__ __forceinline__ void unpack8(uint4 v, float* x) {
    x[0] = bf2f((u16)(v.x & 0xffff)); x[1] = bf2f((u16)(v.x >> 16));
    x[2] = bf2f((u16)(v.y & 0xffff)); x[3] = bf2f((u16)(v.y >> 16));
    x[4] = bf2f((u16)(v.z & 0xffff)); x[5] = bf2f((u16)(v.z >> 16));
    x[6] = bf2f((u16)(v.w & 0xffff)); x[7] = bf2f((u16)(v.w >> 16));
}

__global__ void k_gather(const int* __restrict__ cate, const float* __restrict__ cont,
                         const u16* __restrict__ TQK, const float* __restrict__ CQ,
                         const u16* __restrict__ PEQ, const float* __restrict__ Ut,
                         const float* __restrict__ cu, const float* __restrict__ pu,
                         u16* __restrict__ Qh, u16* __restrict__ Kh,
                         float* __restrict__ u, int h) {
    int tid = threadIdx.x;
    size_t t = (size_t)blockIdx.x*2 + (tid >> 7);
    int r = tid & 127;
    int s = (int)(t & 1023);
    int4 cc = *(const int4*)(cate + t*4);
    float4 cv = ld4(cont + t*4);
    int e = r >> 6;                 // 0=Q, 1=K
    int w = 2*h + e;
    int n = (r & 63)*8;
    const u16* t0 = TQK + ((size_t)(0  + w)*1000 + cc.x)*512 + n;
    const u16* t1 = TQK + ((size_t)(4  + w)*1000 + cc.y)*512 + n;
    const u16* t2 = TQK + ((size_t)(8  + w)*1000 + cc.z)*512 + n;
    const u16* t3 = TQK + ((size_t)(12 + w)*1000 + cc.w)*512 + n;
    const u16* pq = PEQ + ((size_t)w*1024 + s)*512 + n;
    const float* cq = CQ + (size_t)w*2048 + n;
    float a0[8], a1[8], a2[8], a3[8], ap[8];
    unpack8(*(const uint4*)t0, a0); unpack8(*(const uint4*)t1, a1);
    unpack8(*(const uint4*)t2, a2); unpack8(*(const uint4*)t3, a3);
    unpack8(*(const uint4*)pq, ap);
    unsigned int pack[4];
    #pragma unroll
    for (int jp = 0; jp < 4; ++jp) {
        float x0, x1;
        #pragma unroll
        for (int half = 0; half < 2; ++half) {
            int j = jp*2 + half;
            float x = a0[j] + a1[j] + a2[j] + a3[j] + ap[j]
                    + cv.x*cq[j] + cv.y*cq[512+j] + cv.z*cq[1024+j] + cv.w*cq[1536+j];
            if (half == 0) x0 = x; else x1 = x;
        }
        pack[jp] = ((unsigned int)f2bf(x1) << 16) | f2bf(x0);
    }
    u16* op = (e ? Kh : Qh) + t*512 + n;
    *(uint4*)op = make_uint4(pack[0], pack[1], pack[2], pack[3]);
    if (r == 0) {
        float uu = pu[h*1024 + s]
                 + Ut[(0*2 + h)*1000 + cc.x] + Ut[(1*2 + h)*1000 + cc.y]
                 + Ut[(2*2 + h)*1000 + cc.z] + Ut[(3*2 + h)*1000 + cc.w]
                 + cv.x*cu[h*4+0] + cv.y*cu[h*4+1] + cv.z*cu[h*4+2] + cv.w*cu[h*4+3];
        u[(size_t)h*NT + t] = uu;
    }
}

// ---------------- combine per-tile stats (8 m-tiles) ----------------
__global__ void k_stats_combine(const float* __restrict__ Pm, const float* __restrict__ Pd,
                                const float* __restrict__ u, float* __restrict__ m,
                                float* __restrict__ w, int b0) {
    int idx = b0*1024 + blockIdx.x*256 + threadIdx.x;   // b*1024 + k
    int b = idx >> 10, k = idx & 1023;
    float mx = -3.4e38f;
    #pragma unroll
    for (int mt = 0; mt < 8; ++mt) mx = fmaxf(mx, Pm[((size_t)b*8 + mt)*1024 + k]);
    float dd = 0.f;
    #pragma unroll
    for (int mt = 0; mt < 8; ++mt) dd += Pd[((size_t)b*8 + mt)*1024 + k]
                                       * expf(Pm[((size_t)b*8 + mt)*1024 + k] - mx);
    m[idx] = mx;
    w[idx] = u[idx] / dd;
}

// ---------------- logits (S is bf16) ----------------
__global__ void k_logit(const u16* __restrict__ Sb, const float* __restrict__ m,
                        const float* __restrict__ w, float* __restrict__ logits,
                        int b0, int init) {
    size_t tl = blockIdx.x;                  // local row within chunk
    size_t tabs = (size_t)b0*1024 + tl;
    int b = (int)(tabs >> 10);
    const u16* row = Sb + tl*1024;
    const float* mb = m + (size_t)b*1024;
    const float* wb = w + (size_t)b*1024;
    int k = threadIdx.x*4;
    float4 s = ld4bf(row + k);
    float4 mm = ld4(mb + k);
    float4 ww = ld4(wb + k);
    float acc = expf(s.x - mm.x)*ww.x + expf(s.y - mm.y)*ww.y
              + expf(s.z - mm.z)*ww.z + expf(s.w - mm.w)*ww.w;
    acc = blockReduceSum(acc);
    if (threadIdx.x == 0) { if (init) logits[tabs] = acc; else logits[tabs] += acc; }
}

// Output is FLOAT32 (reference returns fp32; harness reads fp32).
__global__ void k_final(const float* __restrict__ logits, float* __restrict__ out) {
    int t = blockIdx.x*256 + threadIdx.x;
    float x = logits[t];
    out[t] = 1.f / (1.f + expf(-x));
}

extern "C" void kernel_launch(void* const* d_in, const int* in_sizes, int n_in,
                              void* d_out, int out_size, void* d_ws, size_t ws_size,
                              hipStream_t stream) {
    const int*   cate = (const int*)d_in[0];
    const float* cont = (const float*)d_in[1];
    Ptrs4f E; E.p[0] = (const float*)d_in[4]; E.p[1] = (const float*)d_in[5];
              E.p[2] = (const float*)d_in[6]; E.p[3] = (const float*)d_in[7];
    const float* Wc    = (const float*)d_in[8];
    const float* Wproj = (const float*)d_in[9];
    Ptrs4f W; W.p[0] = (const float*)d_in[10];  // WQ1
              W.p[1] = (const float*)d_in[11];  // WK1
              W.p[2] = (const float*)d_in[13];  // WQ2
              W.p[3] = (const float*)d_in[14];  // WK2
    const float* WV1 = (const float*)d_in[12];
    const float* WV2 = (const float*)d_in[15];
    const float* W0  = (const float*)d_in[16];
    const float* Wf  = (const float*)d_in[17];

    char* base = (char*)d_ws;
    size_t off = 0;
    auto alloc = [&](size_t bytes) { void* p = base + off; off += (bytes + 255) & ~(size_t)255; return p; };
    u16*   PE16  = (u16*)  alloc(1048576ull*2);
    u16*   E16   = (u16*)  alloc(4ull*1000*128*2);
    u16*   Wt    = (u16*)  alloc(4ull*512*1024*2);
    u16*   WpT   = (u16*)  alloc(4ull*1024*128*2);
    u16*   T16   = (u16*)  alloc(4ull*1000*1024*2);
    u16*   TQK16 = (u16*)  alloc(16ull*1000*512*2);
    u16*   PEQ16 = (u16*)  alloc(4ull*1024*512*2);
    float* Wcp   = (float*)alloc(4*1024*4);
    float* W0f   = (float*)alloc(1024*4);
    float* vv    = (float*)alloc(2*1024*4);
    float* CQ    = (float*)alloc(16*512*4);
    float* Ut    = (float*)alloc(8*1000*4);
    float* cu    = (float*)alloc(8*4);
    float* pu    = (float*)alloc(2*1024*4);
    float* ubuf  = (float*)alloc(2ull*NT*4);
    u16*   Qh    = (u16*)  alloc((size_t)NT*512*2);
    u16*   Kh    = (u16*)  alloc((size_t)NT*512*2);
    float* Pm    = (float*)alloc(32ull*8*1024*4);
    float* Pd    = (float*)alloc(32ull*8*1024*4);
    float* mbuf  = (float*)alloc(32*1024*4);
    float* wbuf  = (float*)alloc(32*1024*4);
    float* logits= (float*)alloc((size_t)NT*4);
    size_t sChunkBytes = (size_t)SS*SS*2;     // bf16 S
    size_t remain = (ws_size > off) ? (ws_size - off) : 0;
    int NB = (int)(remain / sChunkBytes);
    if (NB > 32) NB = 32;
    if (NB < 1) NB = 1;
    u16* Sbuf = (u16*)(base + off);

    const float alpha = 0.044194173824159216f;   // 1/sqrt(512)

    k_pe16<<<1024, 512, 0, stream>>>(PE16);
    k_cvtE<<<dim3(500, 4), 256, 0, stream>>>(E, E16);
    k_transp<<<dim3(16, 32, 4), dim3(32, 32), 0, stream>>>(W, Wt, 1024, 512);
    Ptrs4f Wp4; for (int f = 0; f < 4; ++f) Wp4.p[f] = Wproj + (size_t)f*128*1024;
    k_transp<<<dim3(32, 4, 4), dim3(32, 32), 0, stream>>>(Wp4, WpT, 128, 1024);
    k_pre1<<<1072, 256, 0, stream>>>(W0, Wf, Wc, Wproj, W0f, Wcp, CQ);
    k_pre2<<<2304, 256, 0, stream>>>(W, WV1, WV2, W0f, Wcp, vv, CQ);
    k_g_T16<<<dim3(8, 8, 4), 256, 0, stream>>>(E16, WpT, T16);
    k_g_TQK<<<dim3(4, 8, 16), 256, 0, stream>>>(T16, Wt, TQK16);
    k_g_PEQ<<<dim3(4, 8, 4), 256, 0, stream>>>(PE16, Wt, PEQ16);
    k_dots<<<10056, 256, 0, stream>>>(T16, PE16, Wcp, vv, Ut, pu, cu);

    for (int h = 0; h < 2; ++h) {
        k_gather<<<NT/2, 256, 0, stream>>>(cate, cont, TQK16, CQ, PEQ16, Ut, cu, pu, Qh, Kh, ubuf, h);
        for (int b0 = 0; b0 < 32; b0 += NB) {
            int nb = (32 - b0 < NB) ? (32 - b0) : NB;
            k_g_S<<<dim3(8, 8, nb), 256, 0, stream>>>(Qh + (size_t)b0*SS*AT, Kh + (size_t)b0*SS*AT, Sbuf, alpha, Pm, Pd, b0);
            k_stats_combine<<<nb*4, 256, 0, stream>>>(Pm, Pd, ubuf + (size_t)h*NT, mbuf, wbuf, b0);
            k_logit<<<nb*SS, 256, 0, stream>>>(Sbuf, mbuf, wbuf, logits, b0, h == 0 ? 1 : 0);
        }
    }
    k_final<<<128, 256, 0, stream>>>(logits, (float*)d_out);
}

// Round 9
// 424.872 us; speedup vs baseline: 2.0714x; 1.0524x over previous
//
#include <hip/hip_runtime.h>
#include <hip/hip_bf16.h>
#include <math.h>

#define BB    32
#define SS    1024
#define HID   1024
#define AT    512
#define NVOC  1000
#define NT    (BB*SS)

typedef unsigned short u16;
typedef __attribute__((ext_vector_type(8))) short s16x8;   // 8 bf16 (4 VGPRs)
typedef __attribute__((ext_vector_type(4))) float f32x4;   // MFMA acc

__device__ __forceinline__ float bf2f(u16 u) {
    union { unsigned int i; float f; } x; x.i = ((unsigned int)u) << 16; return x.f;
}
__device__ __forceinline__ u16 f2bf(float f) {
    union { float f; unsigned int i; } u; u.f = f;
    unsigned int r = u.i + 0x7fffu + ((u.i >> 16) & 1u);
    return (u16)(r >> 16);
}
__device__ __forceinline__ float4 ld4(const float* p) { return *(const float4*)p; }
__device__ __forceinline__ float4 ld4bf(const u16* p) {
    ushort4 v = *(const ushort4*)p;
    return make_float4(bf2f(v.x), bf2f(v.y), bf2f(v.z), bf2f(v.w));
}

// async global->LDS, 16B per lane; LDS dest = uniform base + lane*16 [m97]
__device__ __forceinline__ void gld16(const u16* g, u16* l) {
    __builtin_amdgcn_global_load_lds(
        (const __attribute__((address_space(1))) unsigned int*)g,
        (__attribute__((address_space(3))) unsigned int*)l,
        16, 0, 0);
}

struct Ptrs4f { const float* p[4]; };

__device__ __forceinline__ float blockReduceSum(float x) {
    #pragma unroll
    for (int off = 32; off > 0; off >>= 1) x += __shfl_down(x, off, 64);
    __shared__ float tmp[4];
    int lane = threadIdx.x & 63, wid = threadIdx.x >> 6;
    if (lane == 0) tmp[wid] = x;
    __syncthreads();
    if (threadIdx.x == 0) x = tmp[0] + tmp[1] + tmp[2] + tmp[3];
    return x; // valid on thread 0 only
}
__device__ __forceinline__ float waveReduceSum(float x) {
    #pragma unroll
    for (int off = 32; off > 0; off >>= 1) x += __shfl_down(x, off, 64);
    return x; // valid on lane 0
}

// ---------------- PE table, bf16 direct ----------------
__global__ void k_pe16(u16* __restrict__ PE16) {
    int s = blockIdx.x, i = threadIdx.x;               // 512 threads
    const float l2_10000 = 13.287712379549449f;        // log2(10000)
    float denom = exp2f((2.f * (float)i / 1024.f) * l2_10000);
    float ang = (float)s / denom;
    unsigned int pack = ((unsigned int)f2bf(cosf(ang)) << 16) | f2bf(sinf(ang));
    *(unsigned int*)(PE16 + (size_t)s*1024 + 2*i) = pack;
}
__global__ void k_cvt(const float* __restrict__ in, u16* __restrict__ out, int n) {
    int i = blockIdx.x*256 + threadIdx.x;
    if (i < n) out[i] = f2bf(in[i]);
}
__global__ void k_cvtE(Ptrs4f E, u16* __restrict__ out) {
    int f = blockIdx.y;
    int i = blockIdx.x*256 + threadIdx.x;               // 0..127999
    if (i < 128000) out[(size_t)f*128000 + i] = f2bf(E.p[f][i]);
}

// ---------------- transpose fp32 -> bf16: out[c][r] = in[r][c] ----------------
__global__ void k_transp(Ptrs4f src, u16* __restrict__ dst, int R, int C) {
    const float* in = src.p[blockIdx.z];
    u16* out = dst + (size_t)blockIdx.z * R * C;
    int r0 = blockIdx.y*32, c0 = blockIdx.x*32;
    __shared__ float tt[32][33];
    tt[threadIdx.y][threadIdx.x] = in[(size_t)(r0 + threadIdx.y)*C + c0 + threadIdx.x];
    __syncthreads();
    out[(size_t)(c0 + threadIdx.y)*R + r0 + threadIdx.x] = f2bf(tt[threadIdx.x][threadIdx.y]);
}

// ---------------- stage A: W0f rows (1024) + Wcp (16) + CQ zero (32) ----------------
__global__ void k_pre1(const float* __restrict__ W0, const float* __restrict__ Wf,
                       const float* __restrict__ Wc, const float* __restrict__ Wproj,
                       float* __restrict__ W0f, float* __restrict__ Wcp, float* __restrict__ CQ) {
    int blk = blockIdx.x, tid = threadIdx.x;
    if (blk < 1024) {
        const float* row = W0 + (size_t)blk*1024;
        float a = 0.f;
        for (int j = tid; j < 1024; j += 256) a += row[j] * Wf[j];
        a = blockReduceSum(a);
        if (tid == 0) W0f[blk] = a;
    } else if (blk < 1040) {
        int r = blk - 1024; int c = r >> 2, is = r & 3; int i = is*256 + tid;
        float a = 0.f;
        for (int j = 0; j < 512; ++j) a += Wc[c*512 + j] * Wproj[(size_t)(512 + j)*1024 + i];
        Wcp[c*1024 + i] = a;
    } else {
        int r = blk - 1040;
        CQ[r*256 + tid] = 0.f;
    }
}

// ---------------- stage B: v (2048) + CQ j-split atomic (256) ----------------
__global__ void k_pre2(Ptrs4f W, const float* __restrict__ WV1, const float* __restrict__ WV2,
                       const float* __restrict__ W0f, const float* __restrict__ Wcp,
                       float* __restrict__ v, float* __restrict__ CQ) {
    int blk = blockIdx.x, tid = threadIdx.x;
    if (blk < 2048) {
        int h = blk >> 10, i = blk & 1023;
        const float* WV = h ? WV2 : WV1;
        const float* wf = W0f + h*512;
        float a = 0.f;
        for (int aa = tid; aa < 512; aa += 256) a += WV[(size_t)i*512 + aa] * wf[aa];
        a = blockReduceSum(a);
        if (tid == 0) v[h*1024 + i] = a;
    } else {
        int r = blk - 2048;              // 0..255
        int ns = r & 1, wc = (r >> 1) & 15, jc = r >> 5;   // jc 0..7
        int w = wc & 3, c = wc >> 2; int n = ns*256 + tid;
        const float* Ww = W.p[w];
        float a = 0.f;
        for (int j = jc*128; j < jc*128 + 128; ++j) a += Wcp[c*1024 + j] * Ww[(size_t)j*512 + n];
        atomicAdd(&CQ[(size_t)(w*4 + c)*512 + n], a);
    }
}

// ---------------- stage C: pv[f][h] = Wproj_f @ v_h  (1024 blocks) ----------------
__global__ void k_pre3(const float* __restrict__ Wproj, const float* __restrict__ v,
                       float* __restrict__ pv) {
    int blk = blockIdx.x, tid = threadIdx.x;   // blk = (f*2+h)*128 + i
    int i = blk & 127, fh = blk >> 7; int f = fh >> 1, h = fh & 1;
    const float* row = Wproj + (size_t)(f*128 + i)*1024;
    const float* vh = v + h*1024;
    float a = 0.f;
    for (int j = tid; j < 1024; j += 256) a += row[j] * vh[j];
    a = blockReduceSum(a);
    if (tid == 0) pv[(size_t)fh*128 + i] = a;
}

// ---------------- MFMA GEMM: C[M,N] = alpha * A[M,K] @ B[N,K]^T (bf16 in) ----------------
// BK=64, global_load_lds width 16, XOR-swizzled k-chunks (conflict-free, R8: conflicts -> 0).
// STATS: quantize ONCE to bf16 bits (store bits), stats from the quantized values, exp2 domain.
__device__ __forceinline__ void cstore(float* p, float v) { *p = v; }
__device__ __forceinline__ void cstore(u16* p, float v)   { *p = f2bf(v); }

template<typename CT, bool STATS, bool CTRANS>
__device__ __forceinline__ void mfma_gemm(const u16* __restrict__ A, const u16* __restrict__ B,
                                          CT* __restrict__ C, int M, int N, int K, float alpha,
                                          float* __restrict__ Pm, float* __restrict__ Pd,
                                          int m0, int n0) {
    __shared__ u16 As[128*64];
    __shared__ u16 Bs[128*64];
    const int tid = threadIdx.x;
    const int wave = tid >> 6, lane = tid & 63;
    const int quad = lane >> 4, l16 = lane & 15;
    const int wm = (wave >> 1)*64, wn = (wave & 1)*64;
    const int srow = lane >> 3;                 // 0..7 within the 8-row group
    const int scol = ((lane & 7) ^ srow) * 8;   // swizzled global k-chunk
    f32x4 acc[4][4] = {};

    for (int k0 = 0; k0 < K; k0 += 64) {
        #pragma unroll
        for (int p = 0; p < 4; ++p) {
            int rb = wave*32 + p*8;
            gld16(A + (size_t)(m0 + rb + srow)*K + k0 + scol, As + rb*64);
            gld16(B + (size_t)(n0 + rb + srow)*K + k0 + scol, Bs + rb*64);
        }
        __syncthreads();
        #pragma unroll
        for (int kk = 0; kk < 2; ++kk) {
            s16x8 af[4], bf[4];
            #pragma unroll
            for (int i = 0; i < 4; ++i) {
                int row = wm + i*16 + l16;
                af[i] = *(const s16x8*)(As + row*64 + (((kk*4 + quad) ^ (row & 7)) * 8));
            }
            #pragma unroll
            for (int j = 0; j < 4; ++j) {
                int row = wn + j*16 + l16;
                bf[j] = *(const s16x8*)(Bs + row*64 + (((kk*4 + quad) ^ (row & 7)) * 8));
            }
            #pragma unroll
            for (int i = 0; i < 4; ++i)
                #pragma unroll
                for (int j = 0; j < 4; ++j)
                    acc[i][j] = __builtin_amdgcn_mfma_f32_16x16x32_bf16(af[i], bf[j], acc[i][j], 0, 0, 0);
        }
        __syncthreads();
    }
    // C/D layout: col = lane&15, row = quad*4 + reg  [measured m89/m91]
    if (STATS) {
        u16 qb[4][4][4];
        #pragma unroll
        for (int i = 0; i < 4; ++i)
            #pragma unroll
            for (int j = 0; j < 4; ++j)
                #pragma unroll
                for (int r = 0; r < 4; ++r) {
                    u16 b = f2bf(acc[i][j][r] * alpha);
                    qb[i][j][r] = b;
                    acc[i][j][r] = bf2f(b);
                }
        #pragma unroll
        for (int i = 0; i < 4; ++i)
            #pragma unroll
            for (int r = 0; r < 4; ++r) {
                int gm = m0 + wm + i*16 + quad*4 + r;
                #pragma unroll
                for (int j = 0; j < 4; ++j) {
                    int gn = n0 + wn + j*16 + l16;
                    ((u16*)C)[(size_t)gm*N + gn] = qb[i][j][r];
                }
            }
        // per-tile column (query-axis) stats in exp2 domain
        __shared__ float sMax[4][64];
        __shared__ float sSum[4][64];
        #pragma unroll
        for (int j = 0; j < 4; ++j) {
            float mx = -3.4e38f;
            #pragma unroll
            for (int i = 0; i < 4; ++i)
                #pragma unroll
                for (int r = 0; r < 4; ++r) mx = fmaxf(mx, acc[i][j][r]);
            mx = fmaxf(mx, __shfl_xor(mx, 16, 64));
            mx = fmaxf(mx, __shfl_xor(mx, 32, 64));
            float sm = 0.f;
            #pragma unroll
            for (int i = 0; i < 4; ++i)
                #pragma unroll
                for (int r = 0; r < 4; ++r) sm += exp2f(acc[i][j][r] - mx);
            sm += __shfl_xor(sm, 16, 64);
            sm += __shfl_xor(sm, 32, 64);
            if (quad == 0) { sMax[wave][j*16 + l16] = mx; sSum[wave][j*16 + l16] = sm; }
        }
        __syncthreads();
        if (tid < 128) {
            int c = tid;
            int w0 = (c < 64) ? 0 : 1, ci = c & 63;
            float m0v = sMax[w0][ci],     s0 = sSum[w0][ci];
            float m1v = sMax[w0 + 2][ci], s1 = sSum[w0 + 2][ci];
            float mm = fmaxf(m0v, m1v);
            float ss = s0 * exp2f(m0v - mm) + s1 * exp2f(m1v - mm);
            Pm[n0 + c] = mm;     // caller pre-offsets Pm/Pd by (b*8 + mtile)*1024
            Pd[n0 + c] = ss;
        }
    } else {
        #pragma unroll
        for (int i = 0; i < 4; ++i) {
            #pragma unroll
            for (int r = 0; r < 4; ++r) {
                int gm = m0 + wm + i*16 + quad*4 + r;
                if (gm < M) {
                    #pragma unroll
                    for (int j = 0; j < 4; ++j) {
                        int gn = n0 + wn + j*16 + l16;
                        if (CTRANS) cstore(C + (size_t)gn*M + gm, acc[i][j][r] * alpha);
                        else        cstore(C + (size_t)gm*N + gn, acc[i][j][r] * alpha);
                    }
                }
            }
        }
    }
}

// PW^T[f][w] (512x128) = (Wproj_f @ W_w)^T   -- M=128,K=1024,N=512, CTRANS
__global__ __launch_bounds__(256) void k_g_PW(const u16* __restrict__ Wp16, const u16* __restrict__ Wt,
                                              u16* __restrict__ PWT) {
    int f = blockIdx.z >> 2, w = blockIdx.z & 3;
    mfma_gemm<u16,false,true>(Wp16 + (size_t)f*128*1024, Wt + (size_t)w*512*1024,
                              PWT + (size_t)blockIdx.z*512*128, 128, 512, 1024, 1.f,
                              nullptr, nullptr, 0, blockIdx.x*128);
}
// TQK[f][w] = E_f @ PW_fw   -- M=1000,K=128,N=512
__global__ __launch_bounds__(256) void k_g_TQK(const u16* __restrict__ E16, const u16* __restrict__ PWT,
                                               u16* __restrict__ TQK16) {
    int f = blockIdx.z >> 2;
    mfma_gemm<u16,false,false>(E16 + (size_t)f*128000, PWT + (size_t)blockIdx.z*512*128,
                   TQK16 + (size_t)blockIdx.z*1000*512, 1000, 512, 128, 1.f, nullptr, nullptr,
                   blockIdx.y*128, blockIdx.x*128);
}
__global__ __launch_bounds__(256) void k_g_PEQ(const u16* __restrict__ PE16, const u16* __restrict__ Wt, u16* __restrict__ PEQ16) {
    mfma_gemm<u16,false,false>(PE16, Wt + (size_t)blockIdx.z*512*1024, PEQ16 + (size_t)blockIdx.z*1024*512,
                         1024, 512, 1024, 1.f, nullptr, nullptr, blockIdx.y*128, blockIdx.x*128);
}
// scores (bf16, exp2-domain: alpha includes log2e) + fused per-tile column stats; XCD-swizzled
__global__ __launch_bounds__(256) void k_g_S(const u16* __restrict__ Q, const u16* __restrict__ K,
                                             u16* __restrict__ Sb, float alpha,
                                             float* __restrict__ Pm, float* __restrict__ Pd, int b0) {
    size_t b = blockIdx.z;
    int bx = (blockIdx.x % 4)*2 + (blockIdx.y % 2);
    int by = (blockIdx.x / 4)*4 + (blockIdx.y / 2);
    size_t po = ((b0 + b)*8 + by)*1024;
    mfma_gemm<u16,true,false>(Q + b*SS*AT, K + b*SS*AT, Sb + b*SS*SS, 1024, 1024, 512, alpha,
                        Pm + po, Pd + po, by*128, bx*128);
}

// ---------------- dots: Ut (2000 blk, wave-dots over E16) + pu (2048) + cu (8) ----------------
__global__ void k_dots(const u16* __restrict__ E16, const u16* __restrict__ PE16,
                       const float* __restrict__ Wcp, const float* __restrict__ v,
                       const float* __restrict__ pv,
                       float* __restrict__ Ut, float* __restrict__ pu, float* __restrict__ cu) {
    int id = blockIdx.x;
    if (id < 2000) {
        int wave = threadIdx.x >> 6, lane = threadIdx.x & 63;
        int d = id*4 + wave;                 // < 8000
        int f = d / 2000, h = (d / 1000) & 1, r = d % 1000;
        unsigned int e2 = *(const unsigned int*)(E16 + ((size_t)f*1000 + r)*128 + lane*2);
        const float* pvp = pv + (size_t)(f*2 + h)*128 + lane*2;
        float a = bf2f((u16)(e2 & 0xffff)) * pvp[0] + bf2f((u16)(e2 >> 16)) * pvp[1];
        a = waveReduceSum(a);
        if (lane == 0) Ut[(size_t)(f*2 + h)*1000 + r] = a;
    } else if (id < 4048) {
        int tq = id - 2000; int h = tq >> 10, s = tq & 1023;
        float4 a = ld4bf(PE16 + (size_t)s*1024 + threadIdx.x*4);
        float4 b = ld4(v + h*1024 + threadIdx.x*4);
        float p = a.x*b.x + a.y*b.y + a.z*b.z + a.w*b.w;
        p = blockReduceSum(p);
        if (threadIdx.x == 0) pu[h*1024 + s] = p;
    } else {
        int tq = id - 4048; int h = tq >> 2, c = tq & 3;
        float4 a = ld4(Wcp + c*1024 + threadIdx.x*4);
        float4 b = ld4(v + h*1024 + threadIdx.x*4);
        float p = a.x*b.x + a.y*b.y + a.z*b.z + a.w*b.w;
        p = blockReduceSum(p);
        if (threadIdx.x == 0) cu[h*4 + c] = p;
    }
}

// ---------------- gather for head h: 2 tokens/block, 8 bf16/thread ----------------
__device__ __forceinline__ void unpack8(uint4 v, float* x) {
    x[0] = bf2f((u16)(v.x & 0xffff)); x[1] = bf2f((u16)(v.x >> 16));
    x[2] = bf2f((u16)(v.y & 0xffff)); x[3] = bf2f((u16)(v.y >> 16));
    x[4] = bf2f((u16)(v.z & 0xffff)); x[5] = bf2f((u16)(v.z >> 16));
    x[6] = bf2f((u16)(v.w & 0xffff)); x[7] = bf2f((u16)(v.w >> 16));
}

__global__ void k_gather(const int* __restrict__ cate, const float* __restrict__ cont,
                         const u16* __restrict__ TQK, const float* __restrict__ CQ,
                         const u16* __restrict__ PEQ, const float* __restrict__ Ut,
                         const float* __restrict__ cu, const float* __restrict__ pu,
                         u16* __restrict__ Qh, u16* __restrict__ Kh,
                         float* __restrict__ u, int h) {
    int tid = threadIdx.x;
    size_t t = (size_t)blockIdx.x*2 + (tid >> 7);
    int r = tid & 127;
    int s = (int)(t & 1023);
    int4 cc = *(const int4*)(cate + t*4);
    float4 cv = ld4(cont + t*4);
    int e = r >> 6;                 // 0=Q, 1=K
    int w = 2*h + e;
    int n = (r & 63)*8;
    const u16* t0 = TQK + ((size_t)(0*4  + w)*1000 + cc.x)*512 + n;
    const u16* t1 = TQK + ((size_t)(1*4  + w)*1000 + cc.y)*512 + n;
    const u16* t2 = TQK + ((size_t)(2*4  + w)*1000 + cc.z)*512 + n;
    const u16* t3 = TQK + ((size_t)(3*4  + w)*1000 + cc.w)*512 + n;
    const u16* pq = PEQ + ((size_t)w*1024 + s)*512 + n;
    const float* cq = CQ + (size_t)w*2048 + n;
    float a0[8], a1[8], a2[8], a3[8], ap[8];
    unpack8(*(const uint4*)t0, a0); unpack8(*(const uint4*)t1, a1);
    unpack8(*(const uint4*)t2, a2); unpack8(*(const uint4*)t3, a3);
    unpack8(*(const uint4*)pq, ap);
    unsigned int pack[4];
    #pragma unroll
    for (int jp = 0; jp < 4; ++jp) {
        float x0, x1;
        #pragma unroll
        for (int half = 0; half < 2; ++half) {
            int j = jp*2 + half;
            float x = a0[j] + a1[j] + a2[j] + a3[j] + ap[j]
                    + cv.x*cq[j] + cv.y*cq[512+j] + cv.z*cq[1024+j] + cv.w*cq[1536+j];
            if (half == 0) x0 = x; else x1 = x;
        }
        pack[jp] = ((unsigned int)f2bf(x1) << 16) | f2bf(x0);
    }
    u16* op = (e ? Kh : Qh) + t*512 + n;
    *(uint4*)op = make_uint4(pack[0], pack[1], pack[2], pack[3]);
    if (r == 0) {
        float uu = pu[h*1024 + s]
                 + Ut[(0*2 + h)*1000 + cc.x] + Ut[(1*2 + h)*1000 + cc.y]
                 + Ut[(2*2 + h)*1000 + cc.z] + Ut[(3*2 + h)*1000 + cc.w]
                 + cv.x*cu[h*4+0] + cv.y*cu[h*4+1] + cv.z*cu[h*4+2] + cv.w*cu[h*4+3];
        u[(size_t)h*NT + t] = uu;
    }
}

// ---------------- combine per-tile stats (8 m-tiles), exp2 domain ----------------
__global__ void k_stats_combine(const float* __restrict__ Pm, const float* __restrict__ Pd,
                                const float* __restrict__ u, float* __restrict__ m,
                                float* __restrict__ w, int b0) {
    int idx = b0*1024 + blockIdx.x*256 + threadIdx.x;   // b*1024 + k
    int b = idx >> 10, k = idx & 1023;
    float mx = -3.4e38f;
    #pragma unroll
    for (int mt = 0; mt < 8; ++mt) mx = fmaxf(mx, Pm[((size_t)b*8 + mt)*1024 + k]);
    float dd = 0.f;
    #pragma unroll
    for (int mt = 0; mt < 8; ++mt) dd += Pd[((size_t)b*8 + mt)*1024 + k]
                                       * exp2f(Pm[((size_t)b*8 + mt)*1024 + k] - mx);
    m[idx] = mx;
    w[idx] = u[idx] / dd;
}

// ---------------- logits (S bf16 in exp2 domain): wave-per-row, no barriers ----------------
__global__ void k_logit(const u16* __restrict__ Sb, const float* __restrict__ m,
                        const float* __restrict__ w, float* __restrict__ logits,
                        int b0, int init) {
    int wave = threadIdx.x >> 6, lane = threadIdx.x & 63;
    size_t tl = (size_t)blockIdx.x*4 + wave;
    size_t tabs = (size_t)b0*1024 + tl;
    int b = (int)(tabs >> 10);
    const u16* row = Sb + tl*1024;
    const float* mb = m + (size_t)b*1024;
    const float* wb = w + (size_t)b*1024;
    float acc = 0.f;
    #pragma unroll
    for (int half = 0; half < 2; ++half) {
        int k = lane*8 + half*512;
        float4 s0 = ld4bf(row + k), s1 = ld4bf(row + k + 4);
        float4 m0 = ld4(mb + k),    m1 = ld4(mb + k + 4);
        float4 w0 = ld4(wb + k),    w1 = ld4(wb + k + 4);
        acc += exp2f(s0.x - m0.x)*w0.x + exp2f(s0.y - m0.y)*w0.y
             + exp2f(s0.z - m0.z)*w0.z + exp2f(s0.w - m0.w)*w0.w
             + exp2f(s1.x - m1.x)*w1.x + exp2f(s1.y - m1.y)*w1.y
             + exp2f(s1.z - m1.z)*w1.z + exp2f(s1.w - m1.w)*w1.w;
    }
    acc = waveReduceSum(acc);
    if (lane == 0) { if (init) logits[tabs] = acc; else logits[tabs] += acc; }
}

// Output is FLOAT32 (reference returns fp32; harness reads fp32).
__global__ void k_final(const float* __restrict__ logits, float* __restrict__ out) {
    int t = blockIdx.x*256 + threadIdx.x;
    float x = logits[t];
    out[t] = 1.f / (1.f + expf(-x));
}

extern "C" void kernel_launch(void* const* d_in, const int* in_sizes, int n_in,
                              void* d_out, int out_size, void* d_ws, size_t ws_size,
                              hipStream_t stream) {
    const int*   cate = (const int*)d_in[0];
    const float* cont = (const float*)d_in[1];
    Ptrs4f E; E.p[0] = (const float*)d_in[4]; E.p[1] = (const float*)d_in[5];
              E.p[2] = (const float*)d_in[6]; E.p[3] = (const float*)d_in[7];
    const float* Wc    = (const float*)d_in[8];
    const float* Wproj = (const float*)d_in[9];
    Ptrs4f W; W.p[0] = (const float*)d_in[10];  // WQ1
              W.p[1] = (const float*)d_in[11];  // WK1
              W.p[2] = (const float*)d_in[13];  // WQ2
              W.p[3] = (const float*)d_in[14];  // WK2
    const float* WV1 = (const float*)d_in[12];
    const float* WV2 = (const float*)d_in[15];
    const float* W0  = (const float*)d_in[16];
    const float* Wf  = (const float*)d_in[17];

    char* base = (char*)d_ws;
    size_t off = 0;
    auto alloc = [&](size_t bytes) { void* p = base + off; off += (bytes + 255) & ~(size_t)255; return p; };
    u16*   PE16  = (u16*)  alloc(1048576ull*2);
    u16*   E16   = (u16*)  alloc(4ull*1000*128*2);
    u16*   Wt    = (u16*)  alloc(4ull*512*1024*2);
    u16*   Wp16  = (u16*)  alloc(512ull*1024*2);
    u16*   PWT   = (u16*)  alloc(16ull*512*128*2);
    u16*   TQK16 = (u16*)  alloc(16ull*1000*512*2);
    u16*   PEQ16 = (u16*)  alloc(4ull*1024*512*2);
    float* Wcp   = (float*)alloc(4*1024*4);
    float* W0f   = (float*)alloc(1024*4);
    float* vv    = (float*)alloc(2*1024*4);
    float* CQ    = (float*)alloc(16*512*4);
    float* pvb   = (float*)alloc(8*128*4);
    float* Ut    = (float*)alloc(8*1000*4);
    float* cu    = (float*)alloc(8*4);
    float* pu    = (float*)alloc(2*1024*4);
    float* ubuf  = (float*)alloc(2ull*NT*4);
    u16*   Qh    = (u16*)  alloc((size_t)NT*512*2);
    u16*   Kh    = (u16*)  alloc((size_t)NT*512*2);
    float* Pm    = (float*)alloc(32ull*8*1024*4);
    float* Pd    = (float*)alloc(32ull*8*1024*4);
    float* mbuf  = (float*)alloc(32*1024*4);
    float* wbuf  = (float*)alloc(32*1024*4);
    float* logits= (float*)alloc((size_t)NT*4);
    size_t sChunkBytes = (size_t)SS*SS*2;     // bf16 S
    size_t remain = (ws_size > off) ? (ws_size - off) : 0;
    int NB = (int)(remain / sChunkBytes);
    if (NB > 32) NB = 32;
    if (NB < 1) NB = 1;
    u16* Sbuf = (u16*)(base + off);

    const float alpha = 0.06375954951107036f;   // log2(e)/sqrt(512): exp2 domain

    k_pe16<<<1024, 512, 0, stream>>>(PE16);
    k_cvtE<<<dim3(500, 4), 256, 0, stream>>>(E, E16);
    k_cvt<<<2048, 256, 0, stream>>>(Wproj, Wp16, 524288);
    k_transp<<<dim3(16, 32, 4), dim3(32, 32), 0, stream>>>(W, Wt, 1024, 512);
    k_pre1<<<1072, 256, 0, stream>>>(W0, Wf, Wc, Wproj, W0f, Wcp, CQ);
    k_pre2<<<2304, 256, 0, stream>>>(W, WV1, WV2, W0f, Wcp, vv, CQ);
    k_pre3<<<1024, 256, 0, stream>>>(Wproj, vv, pvb);
    k_g_PW<<<dim3(4, 1, 16), 256, 0, stream>>>(Wp16, Wt, PWT);
    k_g_TQK<<<dim3(4, 8, 16), 256, 0, stream>>>(E16, PWT, TQK16);
    k_g_PEQ<<<dim3(4, 8, 4), 256, 0, stream>>>(PE16, Wt, PEQ16);
    k_dots<<<4056, 256, 0, stream>>>(E16, PE16, Wcp, vv, pvb, Ut, pu, cu);

    for (int h = 0; h < 2; ++h) {
        k_gather<<<NT/2, 256, 0, stream>>>(cate, cont, TQK16, CQ, PEQ16, Ut, cu, pu, Qh, Kh, ubuf, h);
        for (int b0 = 0; b0 < 32; b0 += NB) {
            int nb = (32 - b0 < NB) ? (32 - b0) : NB;
            k_g_S<<<dim3(8, 8, nb), 256, 0, stream>>>(Qh + (size_t)b0*SS*AT, Kh + (size_t)b0*SS*AT, Sbuf, alpha, Pm, Pd, b0);
            k_stats_combine<<<nb*4, 256, 0, stream>>>(Pm, Pd, ubuf + (size_t)h*NT, mbuf, wbuf, b0);
            k_logit<<<nb*256, 256, 0, stream>>>(Sbuf, mbuf, wbuf, logits, b0, h == 0 ? 1 : 0);
        }
    }
    k_final<<<128, 256, 0, stream>>>(logits, (float*)d_out);
}

// Round 10
// 410.388 us; speedup vs baseline: 2.1445x; 1.0353x over previous
//
#include <hip/hip_runtime.h>
#include <hip/hip_bf16.h>
#include <math.h>

#define BB    32
#define SS    1024
#define HID   1024
#define AT    512
#define NVOC  1000
#define NT    (BB*SS)

typedef unsigned short u16;
typedef __attribute__((ext_vector_type(8))) short s16x8;   // 8 bf16 (4 VGPRs)
typedef __attribute__((ext_vector_type(4))) float f32x4;   // MFMA acc

__device__ __forceinline__ float bf2f(u16 u) {
    union { unsigned int i; float f; } x; x.i = ((unsigned int)u) << 16; return x.f;
}
__device__ __forceinline__ u16 f2bf(float f) {
    union { float f; unsigned int i; } u; u.f = f;
    unsigned int r = u.i + 0x7fffu + ((u.i >> 16) & 1u);
    return (u16)(r >> 16);
}
__device__ __forceinline__ float4 ld4(const float* p) { return *(const float4*)p; }
__device__ __forceinline__ float4 ld4bf(const u16* p) {
    ushort4 v = *(const ushort4*)p;
    return make_float4(bf2f(v.x), bf2f(v.y), bf2f(v.z), bf2f(v.w));
}

// async global->LDS, 16B per lane; LDS dest = uniform base + lane*16 [m97]
__device__ __forceinline__ void gld16(const u16* g, u16* l) {
    __builtin_amdgcn_global_load_lds(
        (const __attribute__((address_space(1))) unsigned int*)g,
        (__attribute__((address_space(3))) unsigned int*)l,
        16, 0, 0);
}

struct Ptrs4f { const float* p[4]; };

__device__ __forceinline__ float blockReduceSum(float x) {
    #pragma unroll
    for (int off = 32; off > 0; off >>= 1) x += __shfl_down(x, off, 64);
    __shared__ float tmp[4];
    int lane = threadIdx.x & 63, wid = threadIdx.x >> 6;
    if (lane == 0) tmp[wid] = x;
    __syncthreads();
    if (threadIdx.x == 0) x = tmp[0] + tmp[1] + tmp[2] + tmp[3];
    return x; // valid on thread 0 only
}
__device__ __forceinline__ float waveReduceSum(float x) {
    #pragma unroll
    for (int off = 32; off > 0; off >>= 1) x += __shfl_down(x, off, 64);
    return x; // valid on lane 0
}

// ---------------- PE table, bf16 direct ----------------
__global__ void k_pe16(u16* __restrict__ PE16) {
    int s = blockIdx.x, i = threadIdx.x;               // 512 threads
    const float l2_10000 = 13.287712379549449f;        // log2(10000)
    float denom = exp2f((2.f * (float)i / 1024.f) * l2_10000);
    float ang = (float)s / denom;
    unsigned int pack = ((unsigned int)f2bf(cosf(ang)) << 16) | f2bf(sinf(ang));
    *(unsigned int*)(PE16 + (size_t)s*1024 + 2*i) = pack;
}
__global__ void k_cvt(const float* __restrict__ in, u16* __restrict__ out, int n) {
    int i = blockIdx.x*256 + threadIdx.x;
    if (i < n) out[i] = f2bf(in[i]);
}
__global__ void k_cvtE(Ptrs4f E, u16* __restrict__ out) {
    int f = blockIdx.y;
    int i = blockIdx.x*256 + threadIdx.x;               // 0..127999
    if (i < 128000) out[(size_t)f*128000 + i] = f2bf(E.p[f][i]);
}

// ---------------- transpose fp32 -> bf16: out[c][r] = in[r][c] ----------------
__global__ void k_transp(Ptrs4f src, u16* __restrict__ dst, int R, int C) {
    const float* in = src.p[blockIdx.z];
    u16* out = dst + (size_t)blockIdx.z * R * C;
    int r0 = blockIdx.y*32, c0 = blockIdx.x*32;
    __shared__ float tt[32][33];
    tt[threadIdx.y][threadIdx.x] = in[(size_t)(r0 + threadIdx.y)*C + c0 + threadIdx.x];
    __syncthreads();
    out[(size_t)(c0 + threadIdx.y)*R + r0 + threadIdx.x] = f2bf(tt[threadIdx.x][threadIdx.y]);
}

// ---------------- stage A: W0f rows (1024) + Wcp (16) + CQ zero (32) ----------------
__global__ void k_pre1(const float* __restrict__ W0, const float* __restrict__ Wf,
                       const float* __restrict__ Wc, const float* __restrict__ Wproj,
                       float* __restrict__ W0f, float* __restrict__ Wcp, float* __restrict__ CQ) {
    int blk = blockIdx.x, tid = threadIdx.x;
    if (blk < 1024) {
        const float* row = W0 + (size_t)blk*1024;
        float a = 0.f;
        for (int j = tid; j < 1024; j += 256) a += row[j] * Wf[j];
        a = blockReduceSum(a);
        if (tid == 0) W0f[blk] = a;
    } else if (blk < 1040) {
        int r = blk - 1024; int c = r >> 2, is = r & 3; int i = is*256 + tid;
        float a = 0.f;
        for (int j = 0; j < 512; ++j) a += Wc[c*512 + j] * Wproj[(size_t)(512 + j)*1024 + i];
        Wcp[c*1024 + i] = a;
    } else {
        int r = blk - 1040;
        CQ[r*256 + tid] = 0.f;
    }
}

// ---------------- stage B: v (2048) + CQ j-split atomic (256) ----------------
__global__ void k_pre2(Ptrs4f W, const float* __restrict__ WV1, const float* __restrict__ WV2,
                       const float* __restrict__ W0f, const float* __restrict__ Wcp,
                       float* __restrict__ v, float* __restrict__ CQ) {
    int blk = blockIdx.x, tid = threadIdx.x;
    if (blk < 2048) {
        int h = blk >> 10, i = blk & 1023;
        const float* WV = h ? WV2 : WV1;
        const float* wf = W0f + h*512;
        float a = 0.f;
        for (int aa = tid; aa < 512; aa += 256) a += WV[(size_t)i*512 + aa] * wf[aa];
        a = blockReduceSum(a);
        if (tid == 0) v[h*1024 + i] = a;
    } else {
        int r = blk - 2048;              // 0..255
        int ns = r & 1, wc = (r >> 1) & 15, jc = r >> 5;   // jc 0..7
        int w = wc & 3, c = wc >> 2; int n = ns*256 + tid;
        const float* Ww = W.p[w];
        float a = 0.f;
        for (int j = jc*128; j < jc*128 + 128; ++j) a += Wcp[c*1024 + j] * Ww[(size_t)j*512 + n];
        atomicAdd(&CQ[(size_t)(w*4 + c)*512 + n], a);
    }
}

// ---------------- stage C: pv[f][h] = Wproj_f @ v_h  (1024 blocks) ----------------
__global__ void k_pre3(const float* __restrict__ Wproj, const float* __restrict__ v,
                       float* __restrict__ pv) {
    int blk = blockIdx.x, tid = threadIdx.x;   // blk = (f*2+h)*128 + i
    int i = blk & 127, fh = blk >> 7; int f = fh >> 1, h = fh & 1;
    const float* row = Wproj + (size_t)(f*128 + i)*1024;
    const float* vh = v + h*1024;
    float a = 0.f;
    for (int j = tid; j < 1024; j += 256) a += row[j] * vh[j];
    a = blockReduceSum(a);
    if (tid == 0) pv[(size_t)fh*128 + i] = a;
}

// ---------------- MFMA GEMM: C[M,N] = alpha * A[M,K] @ B[N,K]^T (bf16 in) ----------------
// BK=64, global_load_lds width 16, XOR-swizzled k-chunks (conflict-free, R8).
// STATS: quantize once, PERMUTED 8B stores (lane's 4 j-values contiguous); within each
// aligned 64-col block, stored slot q holds actual col (q&3)*16 + (q>>2). k_logit uses
// wexp pre-permuted identically, so the dot is invariant.
__device__ __forceinline__ void cstore(float* p, float v) { *p = v; }
__device__ __forceinline__ void cstore(u16* p, float v)   { *p = f2bf(v); }

template<typename CT, bool STATS, bool CTRANS>
__device__ __forceinline__ void mfma_gemm(const u16* __restrict__ A, const u16* __restrict__ B,
                                          CT* __restrict__ C, int M, int N, int K, float alpha,
                                          float* __restrict__ Pm, float* __restrict__ Pd,
                                          int m0, int n0) {
    __shared__ u16 As[128*64];
    __shared__ u16 Bs[128*64];
    const int tid = threadIdx.x;
    const int wave = tid >> 6, lane = tid & 63;
    const int quad = lane >> 4, l16 = lane & 15;
    const int wm = (wave >> 1)*64, wn = (wave & 1)*64;
    const int srow = lane >> 3;                 // 0..7 within the 8-row group
    const int scol = ((lane & 7) ^ srow) * 8;   // swizzled global k-chunk
    f32x4 acc[4][4] = {};

    for (int k0 = 0; k0 < K; k0 += 64) {
        #pragma unroll
        for (int p = 0; p < 4; ++p) {
            int rb = wave*32 + p*8;
            gld16(A + (size_t)(m0 + rb + srow)*K + k0 + scol, As + rb*64);
            gld16(B + (size_t)(n0 + rb + srow)*K + k0 + scol, Bs + rb*64);
        }
        __syncthreads();
        #pragma unroll
        for (int kk = 0; kk < 2; ++kk) {
            s16x8 af[4], bf[4];
            #pragma unroll
            for (int i = 0; i < 4; ++i) {
                int row = wm + i*16 + l16;
                af[i] = *(const s16x8*)(As + row*64 + (((kk*4 + quad) ^ (row & 7)) * 8));
            }
            #pragma unroll
            for (int j = 0; j < 4; ++j) {
                int row = wn + j*16 + l16;
                bf[j] = *(const s16x8*)(Bs + row*64 + (((kk*4 + quad) ^ (row & 7)) * 8));
            }
            #pragma unroll
            for (int i = 0; i < 4; ++i)
                #pragma unroll
                for (int j = 0; j < 4; ++j)
                    acc[i][j] = __builtin_amdgcn_mfma_f32_16x16x32_bf16(af[i], bf[j], acc[i][j], 0, 0, 0);
        }
        __syncthreads();
    }
    // C/D layout: col = lane&15, row = quad*4 + reg  [measured m89/m91]
    if (STATS) {
        #pragma unroll
        for (int i = 0; i < 4; ++i)
            #pragma unroll
            for (int r = 0; r < 4; ++r) {
                int gm = m0 + wm + i*16 + quad*4 + r;
                u16 b0 = f2bf(acc[i][0][r] * alpha);
                u16 b1 = f2bf(acc[i][1][r] * alpha);
                u16 b2 = f2bf(acc[i][2][r] * alpha);
                u16 b3 = f2bf(acc[i][3][r] * alpha);
                acc[i][0][r] = bf2f(b0); acc[i][1][r] = bf2f(b1);
                acc[i][2][r] = bf2f(b2); acc[i][3][r] = bf2f(b3);
                unsigned int lo = (unsigned int)b0 | ((unsigned int)b1 << 16);
                unsigned int hi = (unsigned int)b2 | ((unsigned int)b3 << 16);
                *(uint2*)((u16*)C + (size_t)gm*N + n0 + wn + l16*4) = make_uint2(lo, hi);
            }
        // per-tile column (query-axis) stats in exp2 domain (ACTUAL column space)
        __shared__ float sMax[4][64];
        __shared__ float sSum[4][64];
        #pragma unroll
        for (int j = 0; j < 4; ++j) {
            float mx = -3.4e38f;
            #pragma unroll
            for (int i = 0; i < 4; ++i)
                #pragma unroll
                for (int r = 0; r < 4; ++r) mx = fmaxf(mx, acc[i][j][r]);
            mx = fmaxf(mx, __shfl_xor(mx, 16, 64));
            mx = fmaxf(mx, __shfl_xor(mx, 32, 64));
            float sm = 0.f;
            #pragma unroll
            for (int i = 0; i < 4; ++i)
                #pragma unroll
                for (int r = 0; r < 4; ++r) sm += exp2f(acc[i][j][r] - mx);
            sm += __shfl_xor(sm, 16, 64);
            sm += __shfl_xor(sm, 32, 64);
            if (quad == 0) { sMax[wave][j*16 + l16] = mx; sSum[wave][j*16 + l16] = sm; }
        }
        __syncthreads();
        if (tid < 128) {
            int c = tid;
            int w0 = (c < 64) ? 0 : 1, ci = c & 63;
            float m0v = sMax[w0][ci],     s0 = sSum[w0][ci];
            float m1v = sMax[w0 + 2][ci], s1 = sSum[w0 + 2][ci];
            float mm = fmaxf(m0v, m1v);
            float ss = s0 * exp2f(m0v - mm) + s1 * exp2f(m1v - mm);
            Pm[n0 + c] = mm;     // caller pre-offsets Pm/Pd by (b*8 + mtile)*1024
            Pd[n0 + c] = ss;
        }
    } else {
        #pragma unroll
        for (int i = 0; i < 4; ++i) {
            #pragma unroll
            for (int r = 0; r < 4; ++r) {
                int gm = m0 + wm + i*16 + quad*4 + r;
                if (gm < M) {
                    #pragma unroll
                    for (int j = 0; j < 4; ++j) {
                        int gn = n0 + wn + j*16 + l16;
                        if (CTRANS) cstore(C + (size_t)gn*M + gm, acc[i][j][r] * alpha);
                        else        cstore(C + (size_t)gm*N + gn, acc[i][j][r] * alpha);
                    }
                }
            }
        }
    }
}

// PW^T[f][w] (512x128) = (Wproj_f @ W_w)^T   -- M=128,K=1024,N=512, CTRANS
__global__ __launch_bounds__(256) void k_g_PW(const u16* __restrict__ Wp16, const u16* __restrict__ Wt,
                                              u16* __restrict__ PWT) {
    int f = blockIdx.z >> 2, w = blockIdx.z & 3;
    mfma_gemm<u16,false,true>(Wp16 + (size_t)f*128*1024, Wt + (size_t)w*512*1024,
                              PWT + (size_t)blockIdx.z*512*128, 128, 512, 1024, 1.f,
                              nullptr, nullptr, 0, blockIdx.x*128);
}
// TQK[f][w] = E_f @ PW_fw   -- M=1000,K=128,N=512
__global__ __launch_bounds__(256) void k_g_TQK(const u16* __restrict__ E16, const u16* __restrict__ PWT,
                                               u16* __restrict__ TQK16) {
    int f = blockIdx.z >> 2;
    mfma_gemm<u16,false,false>(E16 + (size_t)f*128000, PWT + (size_t)blockIdx.z*512*128,
                   TQK16 + (size_t)blockIdx.z*1000*512, 1000, 512, 128, 1.f, nullptr, nullptr,
                   blockIdx.y*128, blockIdx.x*128);
}
__global__ __launch_bounds__(256) void k_g_PEQ(const u16* __restrict__ PE16, const u16* __restrict__ Wt, u16* __restrict__ PEQ16) {
    mfma_gemm<u16,false,false>(PE16, Wt + (size_t)blockIdx.z*512*1024, PEQ16 + (size_t)blockIdx.z*1024*512,
                         1024, 512, 1024, 1.f, nullptr, nullptr, blockIdx.y*128, blockIdx.x*128);
}
// scores (bf16, exp2-domain) + fused per-tile column stats; XCD-swizzled
__global__ __launch_bounds__(256) void k_g_S(const u16* __restrict__ Q, const u16* __restrict__ K,
                                             u16* __restrict__ Sb, float alpha,
                                             float* __restrict__ Pm, float* __restrict__ Pd, int b0) {
    size_t b = blockIdx.z;
    int bx = (blockIdx.x % 4)*2 + (blockIdx.y % 2);
    int by = (blockIdx.x / 4)*4 + (blockIdx.y / 2);
    size_t po = ((b0 + b)*8 + by)*1024;
    mfma_gemm<u16,true,false>(Q + b*SS*AT, K + b*SS*AT, Sb + b*SS*SS, 1024, 1024, 512, alpha,
                        Pm + po, Pd + po, by*128, bx*128);
}

// ---------------- dots: Ut (2000 blk, wave-dots over E16) + pu (2048) + cu (8) ----------------
__global__ void k_dots(const u16* __restrict__ E16, const u16* __restrict__ PE16,
                       const float* __restrict__ Wcp, const float* __restrict__ v,
                       const float* __restrict__ pv,
                       float* __restrict__ Ut, float* __restrict__ pu, float* __restrict__ cu) {
    int id = blockIdx.x;
    if (id < 2000) {
        int wave = threadIdx.x >> 6, lane = threadIdx.x & 63;
        int d = id*4 + wave;                 // < 8000
        int f = d / 2000, h = (d / 1000) & 1, r = d % 1000;
        unsigned int e2 = *(const unsigned int*)(E16 + ((size_t)f*1000 + r)*128 + lane*2);
        const float* pvp = pv + (size_t)(f*2 + h)*128 + lane*2;
        float a = bf2f((u16)(e2 & 0xffff)) * pvp[0] + bf2f((u16)(e2 >> 16)) * pvp[1];
        a = waveReduceSum(a);
        if (lane == 0) Ut[(size_t)(f*2 + h)*1000 + r] = a;
    } else if (id < 4048) {
        int tq = id - 2000; int h = tq >> 10, s = tq & 1023;
        float4 a = ld4bf(PE16 + (size_t)s*1024 + threadIdx.x*4);
        float4 b = ld4(v + h*1024 + threadIdx.x*4);
        float p = a.x*b.x + a.y*b.y + a.z*b.z + a.w*b.w;
        p = blockReduceSum(p);
        if (threadIdx.x == 0) pu[h*1024 + s] = p;
    } else {
        int tq = id - 4048; int h = tq >> 2, c = tq & 3;
        float4 a = ld4(Wcp + c*1024 + threadIdx.x*4);
        float4 b = ld4(v + h*1024 + threadIdx.x*4);
        float p = a.x*b.x + a.y*b.y + a.z*b.z + a.w*b.w;
        p = blockReduceSum(p);
        if (threadIdx.x == 0) cu[h*4 + c] = p;
    }
}

// ---------------- gather for head h: 2 tokens/block, 8 bf16/thread ----------------
__device__ __forceinline__ void unpack8(uint4 v, float* x) {
    x[0] = bf2f((u16)(v.x & 0xffff)); x[1] = bf2f((u16)(v.x >> 16));
    x[2] = bf2f((u16)(v.y & 0xffff)); x[3] = bf2f((u16)(v.y >> 16));
    x[4] = bf2f((u16)(v.z & 0xffff)); x[5] = bf2f((u16)(v.z >> 16));
    x[6] = bf2f((u16)(v.w & 0xffff)); x[7] = bf2f((u16)(v.w >> 16));
}

__global__ void k_gather(const int* __restrict__ cate, const float* __restrict__ cont,
                         const u16* __restrict__ TQK, const float* __restrict__ CQ,
                         const u16* __restrict__ PEQ, const float* __restrict__ Ut,
                         const float* __restrict__ cu, const float* __restrict__ pu,
                         u16* __restrict__ Qh, u16* __restrict__ Kh,
                         float* __restrict__ u, int h) {
    int tid = threadIdx.x;
    size_t t = (size_t)blockIdx.x*2 + (tid >> 7);
    int r = tid & 127;
    int s = (int)(t & 1023);
    int4 cc = *(const int4*)(cate + t*4);
    float4 cv = ld4(cont + t*4);
    int e = r >> 6;                 // 0=Q, 1=K
    int w = 2*h + e;
    int n = (r & 63)*8;
    const u16* t0 = TQK + ((size_t)(0*4  + w)*1000 + cc.x)*512 + n;
    const u16* t1 = TQK + ((size_t)(1*4  + w)*1000 + cc.y)*512 + n;
    const u16* t2 = TQK + ((size_t)(2*4  + w)*1000 + cc.z)*512 + n;
    const u16* t3 = TQK + ((size_t)(3*4  + w)*1000 + cc.w)*512 + n;
    const u16* pq = PEQ + ((size_t)w*1024 + s)*512 + n;
    const float* cq = CQ + (size_t)w*2048 + n;
    float a0[8], a1[8], a2[8], a3[8], ap[8];
    unpack8(*(const uint4*)t0, a0); unpack8(*(const uint4*)t1, a1);
    unpack8(*(const uint4*)t2, a2); unpack8(*(const uint4*)t3, a3);
    unpack8(*(const uint4*)pq, ap);
    unsigned int pack[4];
    #pragma unroll
    for (int jp = 0; jp < 4; ++jp) {
        float x0, x1;
        #pragma unroll
        for (int half = 0; half < 2; ++half) {
            int j = jp*2 + half;
            float x = a0[j] + a1[j] + a2[j] + a3[j] + ap[j]
                    + cv.x*cq[j] + cv.y*cq[512+j] + cv.z*cq[1024+j] + cv.w*cq[1536+j];
            if (half == 0) x0 = x; else x1 = x;
        }
        pack[jp] = ((unsigned int)f2bf(x1) << 16) | f2bf(x0);
    }
    u16* op = (e ? Kh : Qh) + t*512 + n;
    *(uint4*)op = make_uint4(pack[0], pack[1], pack[2], pack[3]);
    if (r == 0) {
        float uu = pu[h*1024 + s]
                 + Ut[(0*2 + h)*1000 + cc.x] + Ut[(1*2 + h)*1000 + cc.y]
                 + Ut[(2*2 + h)*1000 + cc.z] + Ut[(3*2 + h)*1000 + cc.w]
                 + cv.x*cu[h*4+0] + cv.y*cu[h*4+1] + cv.z*cu[h*4+2] + cv.w*cu[h*4+3];
        u[(size_t)h*NT + t] = uu;
    }
}

// ---------------- combine per-tile stats (8 m-tiles) -> permuted wexp = u/d * 2^-m ----------------
__global__ void k_stats_combine(const float* __restrict__ Pm, const float* __restrict__ Pd,
                                const float* __restrict__ u, float* __restrict__ wexp, int b0) {
    int idx = b0*1024 + blockIdx.x*256 + threadIdx.x;   // b*1024 + k (actual)
    int b = idx >> 10, k = idx & 1023;
    float mx = -3.4e38f;
    #pragma unroll
    for (int mt = 0; mt < 8; ++mt) mx = fmaxf(mx, Pm[((size_t)b*8 + mt)*1024 + k]);
    float dd = 0.f;
    #pragma unroll
    for (int mt = 0; mt < 8; ++mt) dd += Pd[((size_t)b*8 + mt)*1024 + k]
                                       * exp2f(Pm[((size_t)b*8 + mt)*1024 + k] - mx);
    // permuted slot within the aligned 64-block: q = ((k&15)<<2) | ((k&63)>>4)
    int q = (k & ~63) | (((k & 15) << 2) | ((k & 63) >> 4));
    wexp[((size_t)b << 10) + q] = u[idx] / dd * exp2f(-mx);
}

// ---------------- logits: wave-per-row over permuted S/wexp, no m, no barriers ----------------
__global__ void k_logit(const u16* __restrict__ Sb, const float* __restrict__ wexp,
                        float* __restrict__ logits, int b0, int init) {
    int wave = threadIdx.x >> 6, lane = threadIdx.x & 63;
    size_t tl = (size_t)blockIdx.x*4 + wave;
    size_t tabs = (size_t)b0*1024 + tl;
    int b = (int)(tabs >> 10);
    const u16* row = Sb + tl*1024;
    const float* wb = wexp + ((size_t)b << 10);
    float acc = 0.f;
    #pragma unroll
    for (int half = 0; half < 2; ++half) {
        int k = lane*8 + half*512;
        float4 s0 = ld4bf(row + k), s1 = ld4bf(row + k + 4);
        float4 w0 = ld4(wb + k),    w1 = ld4(wb + k + 4);
        acc += exp2f(s0.x)*w0.x + exp2f(s0.y)*w0.y + exp2f(s0.z)*w0.z + exp2f(s0.w)*w0.w
             + exp2f(s1.x)*w1.x + exp2f(s1.y)*w1.y + exp2f(s1.z)*w1.z + exp2f(s1.w)*w1.w;
    }
    acc = waveReduceSum(acc);
    if (lane == 0) { if (init) logits[tabs] = acc; else logits[tabs] += acc; }
}

// Output is FLOAT32 (reference returns fp32; harness reads fp32).
__global__ void k_final(const float* __restrict__ logits, float* __restrict__ out) {
    int t = blockIdx.x*256 + threadIdx.x;
    float x = logits[t];
    out[t] = 1.f / (1.f + expf(-x));
}

extern "C" void kernel_launch(void* const* d_in, const int* in_sizes, int n_in,
                              void* d_out, int out_size, void* d_ws, size_t ws_size,
                              hipStream_t stream) {
    const int*   cate = (const int*)d_in[0];
    const float* cont = (const float*)d_in[1];
    Ptrs4f E; E.p[0] = (const float*)d_in[4]; E.p[1] = (const float*)d_in[5];
              E.p[2] = (const float*)d_in[6]; E.p[3] = (const float*)d_in[7];
    const float* Wc    = (const float*)d_in[8];
    const float* Wproj = (const float*)d_in[9];
    Ptrs4f W; W.p[0] = (const float*)d_in[10];  // WQ1
              W.p[1] = (const float*)d_in[11];  // WK1
              W.p[2] = (const float*)d_in[13];  // WQ2
              W.p[3] = (const float*)d_in[14];  // WK2
    const float* WV1 = (const float*)d_in[12];
    const float* WV2 = (const float*)d_in[15];
    const float* W0  = (const float*)d_in[16];
    const float* Wf  = (const float*)d_in[17];

    char* base = (char*)d_ws;
    size_t off = 0;
    auto alloc = [&](size_t bytes) { void* p = base + off; off += (bytes + 255) & ~(size_t)255; return p; };
    u16*   PE16  = (u16*)  alloc(1048576ull*2);
    u16*   E16   = (u16*)  alloc(4ull*1000*128*2);
    u16*   Wt    = (u16*)  alloc(4ull*512*1024*2);
    u16*   Wp16  = (u16*)  alloc(512ull*1024*2);
    u16*   PWT   = (u16*)  alloc(16ull*512*128*2);
    u16*   TQK16 = (u16*)  alloc(16ull*1000*512*2);
    u16*   PEQ16 = (u16*)  alloc(4ull*1024*512*2);
    float* Wcp   = (float*)alloc(4*1024*4);
    float* W0f   = (float*)alloc(1024*4);
    float* vv    = (float*)alloc(2*1024*4);
    float* CQ    = (float*)alloc(16*512*4);
    float* pvb   = (float*)alloc(8*128*4);
    float* Ut    = (float*)alloc(8*1000*4);
    float* cu    = (float*)alloc(8*4);
    float* pu    = (float*)alloc(2*1024*4);
    float* ubuf  = (float*)alloc(2ull*NT*4);
    u16*   Qh    = (u16*)  alloc((size_t)NT*512*2);
    u16*   Kh    = (u16*)  alloc((size_t)NT*512*2);
    float* Pm    = (float*)alloc(32ull*8*1024*4);
    float* Pd    = (float*)alloc(32ull*8*1024*4);
    float* wbuf  = (float*)alloc(32*1024*4);
    float* logits= (float*)alloc((size_t)NT*4);
    size_t sChunkBytes = (size_t)SS*SS*2;     // bf16 S
    size_t remain = (ws_size > off) ? (ws_size - off) : 0;
    int NB = (int)(remain / sChunkBytes);
    if (NB > 32) NB = 32;
    if (NB < 1) NB = 1;
    u16* Sbuf = (u16*)(base + off);

    const float alpha = 0.06375954951107036f;   // log2(e)/sqrt(512): exp2 domain

    k_pe16<<<1024, 512, 0, stream>>>(PE16);
    k_cvtE<<<dim3(500, 4), 256, 0, stream>>>(E, E16);
    k_cvt<<<2048, 256, 0, stream>>>(Wproj, Wp16, 524288);
    k_transp<<<dim3(16, 32, 4), dim3(32, 32), 0, stream>>>(W, Wt, 1024, 512);
    k_pre1<<<1072, 256, 0, stream>>>(W0, Wf, Wc, Wproj, W0f, Wcp, CQ);
    k_pre2<<<2304, 256, 0, stream>>>(W, WV1, WV2, W0f, Wcp, vv, CQ);
    k_pre3<<<1024, 256, 0, stream>>>(Wproj, vv, pvb);
    k_g_PW<<<dim3(4, 1, 16), 256, 0, stream>>>(Wp16, Wt, PWT);
    k_g_TQK<<<dim3(4, 8, 16), 256, 0, stream>>>(E16, PWT, TQK16);
    k_g_PEQ<<<dim3(4, 8, 4), 256, 0, stream>>>(PE16, Wt, PEQ16);
    k_dots<<<4056, 256, 0, stream>>>(E16, PE16, Wcp, vv, pvb, Ut, pu, cu);

    for (int h = 0; h < 2; ++h) {
        k_gather<<<NT/2, 256, 0, stream>>>(cate, cont, TQK16, CQ, PEQ16, Ut, cu, pu, Qh, Kh, ubuf, h);
        for (int b0 = 0; b0 < 32; b0 += NB) {
            int nb = (32 - b0 < NB) ? (32 - b0) : NB;
            k_g_S<<<dim3(8, 8, nb), 256, 0, stream>>>(Qh + (size_t)b0*SS*AT, Kh + (size_t)b0*SS*AT, Sbuf, alpha, Pm, Pd, b0);
            k_stats_combine<<<nb*4, 256, 0, stream>>>(Pm, Pd, ubuf + (size_t)h*NT, wbuf, b0);
            k_logit<<<nb*256, 256, 0, stream>>>(Sbuf, wbuf, logits, b0, h == 0 ? 1 : 0);
        }
    }
    k_final<<<128, 256, 0, stream>>>(logits, (float*)d_out);
}